// Round 3
// baseline (783.036 us; speedup 1.0000x reference)
//
#include <hip/hip_runtime.h>
#include <stdint.h>

typedef unsigned short u16;
typedef unsigned int u32;
typedef __attribute__((ext_vector_type(8))) short bf16x8;
typedef __attribute__((ext_vector_type(4))) short s16x4;
typedef __attribute__((ext_vector_type(4))) float f32x4;
typedef __attribute__((ext_vector_type(2))) float f32x2;

#define DEV __device__ __forceinline__

DEV u16 f2bf(float f) {
  union { float f; unsigned u; } v; v.f = f;
  unsigned r = v.u + 0x7fffu + ((v.u >> 16) & 1u);
  return (u16)(r >> 16);
}
DEV int imax(int a, int b) { return a > b ? a : b; }
DEV int imin(int a, int b) { return a < b ? a : b; }

DEV void g2lds16(const u16* g, u16* l) {
  __builtin_amdgcn_global_load_lds(
      (const __attribute__((address_space(1))) void*)g,
      (__attribute__((address_space(3))) void*)l, 16, 0, 0);
}

// ---------------------------------------------------------------------------
// one-shot multi-segment f32 -> bf16 cast
// ---------------------------------------------------------------------------
#define NSEG 11
struct CastTab {
  const float* src[NSEG];
  u16* dst[NSEG];
  int start[NSEG + 1];  // cumulative f32x4 chunk offsets
};

__global__ __launch_bounds__(256) void vas_cast(CastTab t, int total4) {
  int idx = blockIdx.x * 256 + threadIdx.x;
  if (idx >= total4) return;
  int s = 0;
#pragma unroll
  for (int k = 1; k < NSEG; ++k)
    if (idx >= t.start[k]) s = k;
  int local = idx - t.start[s];
  f32x4 f = ((const f32x4*)t.src[s])[local];
  s16x4 o;
  o.x = (short)f2bf(f.x);
  o.y = (short)f2bf(f.y);
  o.z = (short)f2bf(f.z);
  o.w = (short)f2bf(f.w);
  ((s16x4*)t.dst[s])[local] = o;
}

// ---------------------------------------------------------------------------
// bf16 GEMM (m97 structure): C[m,n] = act(sum_k A[m,k]*W[n,k] + bias[n])
// ---------------------------------------------------------------------------
__global__ __launch_bounds__(256) void vas_gemm(
    const u16* __restrict__ A, const u16* __restrict__ W,
    float* __restrict__ C, const float* __restrict__ bias,
    int M, int Nn, int K, int relu) {
  __shared__ u16 As[128 * 32];
  __shared__ u16 Ws[128 * 32];
  const int tid = threadIdx.x;
  const int lane = tid & 63;
  const int wave = tid >> 6;
  const int m0 = blockIdx.x * 128;
  const int n0 = blockIdx.y * 128;
  const int wm = (wave >> 1) * 64;
  const int wn = (wave & 1) * 64;

  f32x4 acc[4][4] = {};

  for (int k0 = 0; k0 < K; k0 += 32) {
#pragma unroll
    for (int hh = 0; hh < 2; ++hh) {
      int c = tid + hh * 256;
      int row = c >> 2, part = c & 3;
      g2lds16(A + (size_t)(m0 + row) * K + (k0 + part * 8), As + c * 8);
      g2lds16(W + (size_t)(n0 + row) * K + (k0 + part * 8), Ws + c * 8);
    }
    __syncthreads();
    bf16x8 af[4], bfr[4];
#pragma unroll
    for (int t = 0; t < 4; ++t)
      af[t] = *(const bf16x8*)(As + (wm + t * 16 + (lane & 15)) * 32 + (lane >> 4) * 8);
#pragma unroll
    for (int t = 0; t < 4; ++t)
      bfr[t] = *(const bf16x8*)(Ws + (wn + t * 16 + (lane & 15)) * 32 + (lane >> 4) * 8);
#pragma unroll
    for (int mi = 0; mi < 4; ++mi)
#pragma unroll
      for (int ni = 0; ni < 4; ++ni)
        acc[mi][ni] = __builtin_amdgcn_mfma_f32_16x16x32_bf16(af[mi], bfr[ni], acc[mi][ni], 0, 0, 0);
    __syncthreads();
  }

#pragma unroll
  for (int mi = 0; mi < 4; ++mi) {
#pragma unroll
    for (int ni = 0; ni < 4; ++ni) {
      int col = n0 + wn + ni * 16 + (lane & 15);
      float bv = bias ? bias[col] : 0.f;
#pragma unroll
      for (int r = 0; r < 4; ++r) {
        int row = m0 + wm + mi * 16 + (lane >> 4) * 4 + r;
        float vv = acc[mi][ni][r] + bv;
        if (relu) vv = fmaxf(vv, 0.f);
        C[(size_t)row * Nn + col] = vv;
      }
    }
  }
}

// ---------------------------------------------------------------------------
// Banded attention softmax -> band buffer only [N,40]
// ---------------------------------------------------------------------------
template <int DIM>
__global__ __launch_bounds__(256) void vas_battn(
    const float* __restrict__ QKV, int ld, int qoff, int koff,
    float* __restrict__ band, int N, float scale) {
  const int lane = threadIdx.x & 63;
  const int wave = threadIdx.x >> 6;
  const int i = blockIdx.x * 4 + wave;
  const int lo = imax(i - 19, 0);
  const int hi = imin(i + 19, N - 1);
  const int nj = hi - lo + 1;
  constexpr int C4 = DIM / 256;
  float logit = 0.f;

  if constexpr (C4 > 0) {
    f32x4 q[C4];
    const float* qrow = QKV + (size_t)i * ld + qoff;
#pragma unroll
    for (int c = 0; c < C4; ++c) q[c] = *(const f32x4*)(qrow + c * 256 + lane * 4);
#pragma unroll 1
    for (int s = 0; s < nj; ++s) {
      const float* kr = QKV + (size_t)(lo + s) * ld + koff;
      float p = 0.f;
#pragma unroll
      for (int c = 0; c < C4; ++c) {
        f32x4 k = *(const f32x4*)(kr + c * 256 + lane * 4);
        p += q[c].x * k.x + q[c].y * k.y + q[c].z * k.z + q[c].w * k.w;
      }
#pragma unroll
      for (int off = 32; off; off >>= 1) p += __shfl_xor(p, off);
      if (lane == s) logit = p;
    }
  } else {
    f32x2 q = *(const f32x2*)(QKV + (size_t)i * ld + qoff + lane * 2);
#pragma unroll 1
    for (int s = 0; s < nj; ++s) {
      f32x2 k = *(const f32x2*)(QKV + (size_t)(lo + s) * ld + koff + lane * 2);
      float p = q.x * k.x + q.y * k.y;
#pragma unroll
      for (int off = 32; off; off >>= 1) p += __shfl_xor(p, off);
      if (lane == s) logit = p;
    }
  }

  logit *= scale;
  float v = (lane < nj) ? logit : -3.4e38f;
  float mx = v;
#pragma unroll
  for (int off = 32; off; off >>= 1) mx = fmaxf(mx, __shfl_xor(mx, off));
  float e = (lane < nj) ? __expf(v - mx) : 0.f;
  float den = e;
#pragma unroll
  for (int off = 32; off; off >>= 1) den += __shfl_xor(den, off);
  if (lane < 40) band[i * 40 + lane] = (lane < nj) ? e / den : 0.f;
}

// ---------------------------------------------------------------------------
// Write full att_comb rows: zeros + video band + audio band. Replaces memset.
// One block per row i; 2N floats per row, f32x4 coalesced.
// ---------------------------------------------------------------------------
__global__ __launch_bounds__(256) void vas_write_att(
    const float* __restrict__ bandV, const float* __restrict__ bandA,
    float* __restrict__ att, int N) {
  const int i = blockIdx.x;
  float* row = att + (size_t)i * 2 * N;
  const int lo = imax(i - 19, 0);
  const int hi = imin(i + 19, N - 1);
  const int loA = N + lo, hiA = N + hi;
  const int nchunks = (2 * N) / 4;
  for (int c = threadIdx.x; c < nchunks; c += 256) {
    int col0 = c * 4;
    f32x4 v = {0.f, 0.f, 0.f, 0.f};
    if (col0 + 3 >= lo && col0 <= hi) {
#pragma unroll
      for (int e = 0; e < 4; ++e) {
        int col = col0 + e;
        if (col >= lo && col <= hi) v[e] = bandV[i * 40 + (col - lo)];
      }
    } else if (col0 + 3 >= loA && col0 <= hiA) {
#pragma unroll
      for (int e = 0; e < 4; ++e) {
        int col = col0 + e;
        if (col >= loA && col <= hiA) v[e] = bandA[i * 40 + (col - loA)];
      }
    }
    ((f32x4*)row)[c] = v;
  }
}

// ---------------------------------------------------------------------------
// y[j,:] = sum_i att[i,j] * V[i,:] (att.T @ V), band only. bf16 out.
// ---------------------------------------------------------------------------
__global__ __launch_bounds__(256) void vas_apply_v(
    const float* __restrict__ QKV, int ld, int voff,
    const float* __restrict__ band, u16* __restrict__ Y, int N) {
  const int j = blockIdx.x;
  const int tid = threadIdx.x;
  __shared__ float a_sh[40];
  const int lo = imax(j - 19, 0);
  const int hi = imin(j + 19, N - 1);
  const int ni = hi - lo + 1;
  if (tid < ni) {
    int i = lo + tid;
    a_sh[tid] = band[i * 40 + (j - imax(i - 19, 0))];
  }
  __syncthreads();
  f32x4 acc = {0.f, 0.f, 0.f, 0.f};
#pragma unroll 1
  for (int s = 0; s < ni; ++s) {
    float a = a_sh[s];
    f32x4 vv = *(const f32x4*)(QKV + (size_t)(lo + s) * ld + voff + tid * 4);
    acc.x += a * vv.x;
    acc.y += a * vv.y;
    acc.z += a * vv.z;
    acc.w += a * vv.w;
  }
  s16x4 o;
  o.x = (short)f2bf(acc.x);
  o.y = (short)f2bf(acc.y);
  o.z = (short)f2bf(acc.z);
  o.w = (short)f2bf(acc.w);
  *(s16x4*)(Y + (size_t)j * 1024 + tid * 4) = o;
}

__global__ __launch_bounds__(256) void vas_apply_a(
    const float* __restrict__ QKV, int ld, int voff,
    const float* __restrict__ band, u16* __restrict__ Y, int N) {
  const int lane = threadIdx.x & 63;
  const int wave = threadIdx.x >> 6;
  const int j = blockIdx.x * 4 + wave;
  __shared__ float a_sh[4][40];
  const int lo = imax(j - 19, 0);
  const int hi = imin(j + 19, N - 1);
  const int ni = hi - lo + 1;
  if (lane < ni) {
    int i = lo + lane;
    a_sh[wave][lane] = band[i * 40 + (j - imax(i - 19, 0))];
  }
  __syncthreads();
  f32x2 acc = {0.f, 0.f};
#pragma unroll 1
  for (int s = 0; s < ni; ++s) {
    float a = a_sh[wave][s];
    f32x2 vv = *(const f32x2*)(QKV + (size_t)(lo + s) * ld + voff + lane * 2);
    acc.x += a * vv.x;
    acc.y += a * vv.y;
  }
  u32 o = (u32)f2bf(acc.x) | ((u32)f2bf(acc.y) << 16);
  *(u32*)(Y + (size_t)j * 128 + lane * 2) = o;
}

// ---------------------------------------------------------------------------
// LayerNorm(O + X)*g + b -> bf16 at [row*outStride + outOff + c]
// ---------------------------------------------------------------------------
__global__ __launch_bounds__(256) void vas_ln_v(
    const float* __restrict__ O, const float* __restrict__ X,
    const float* __restrict__ g, const float* __restrict__ bb,
    u16* __restrict__ out, int outStride, int outOff) {
  const int row = blockIdx.x;
  const int tid = threadIdx.x, lane = tid & 63, wave = tid >> 6;
  __shared__ float shA[4], shB[4];
  f32x4 o4 = ((const f32x4*)(O + (size_t)row * 1024))[tid];
  f32x4 x4 = ((const f32x4*)(X + (size_t)row * 1024))[tid];
  f32x4 v;
  v.x = o4.x + x4.x; v.y = o4.y + x4.y; v.z = o4.z + x4.z; v.w = o4.w + x4.w;
  float s = v.x + v.y + v.z + v.w;
  float s2 = v.x * v.x + v.y * v.y + v.z * v.z + v.w * v.w;
#pragma unroll
  for (int off = 32; off; off >>= 1) {
    s += __shfl_xor(s, off);
    s2 += __shfl_xor(s2, off);
  }
  if (lane == 0) { shA[wave] = s; shB[wave] = s2; }
  __syncthreads();
  float S = shA[0] + shA[1] + shA[2] + shA[3];
  float S2 = shB[0] + shB[1] + shB[2] + shB[3];
  float mu = S / 1024.f;
  float var = S2 / 1024.f - mu * mu;
  float inv = rsqrtf(var + 1e-6f);
  f32x4 gg = ((const f32x4*)g)[tid];
  f32x4 bv = ((const f32x4*)bb)[tid];
  s16x4 o;
  o.x = (short)f2bf((v.x - mu) * inv * gg.x + bv.x);
  o.y = (short)f2bf((v.y - mu) * inv * gg.y + bv.y);
  o.z = (short)f2bf((v.z - mu) * inv * gg.z + bv.z);
  o.w = (short)f2bf((v.w - mu) * inv * gg.w + bv.w);
  *(s16x4*)(out + (size_t)row * outStride + outOff + tid * 4) = o;
}

__global__ __launch_bounds__(128) void vas_ln_a(
    const float* __restrict__ O, const float* __restrict__ X,
    const float* __restrict__ g, const float* __restrict__ bb,
    u16* __restrict__ out, int outStride, int outOff) {
  const int row = blockIdx.x;
  const int tid = threadIdx.x, lane = tid & 63, wave = tid >> 6;
  __shared__ float shA[2], shB[2];
  float v = O[(size_t)row * 128 + tid] + X[(size_t)row * 128 + tid];
  float s = v, s2 = v * v;
#pragma unroll
  for (int off = 32; off; off >>= 1) {
    s += __shfl_xor(s, off);
    s2 += __shfl_xor(s2, off);
  }
  if (lane == 0) { shA[wave] = s; shB[wave] = s2; }
  __syncthreads();
  float S = shA[0] + shA[1];
  float S2 = shB[0] + shB[1];
  float mu = S / 128.f;
  float var = S2 / 128.f - mu * mu;
  float inv = rsqrtf(var + 1e-6f);
  out[(size_t)row * outStride + outOff + tid] = f2bf((v - mu) * inv * g[tid] + bb[tid]);
}

// ---------------------------------------------------------------------------
// head: score[row] = sigmoid( LN(H[row]) . kw + kb )
// ---------------------------------------------------------------------------
__global__ __launch_bounds__(256) void vas_head(
    const float* __restrict__ H, const float* __restrict__ g,
    const float* __restrict__ bb, const float* __restrict__ kw,
    const float* __restrict__ kb, float* __restrict__ score) {
  const int row = blockIdx.x;
  const int tid = threadIdx.x, lane = tid & 63, wave = tid >> 6;
  __shared__ float shA[4], shB[4];
  f32x4 v = ((const f32x4*)(H + (size_t)row * 1024))[tid];
  float s = v.x + v.y + v.z + v.w;
  float s2 = v.x * v.x + v.y * v.y + v.z * v.z + v.w * v.w;
#pragma unroll
  for (int off = 32; off; off >>= 1) {
    s += __shfl_xor(s, off);
    s2 += __shfl_xor(s2, off);
  }
  if (lane == 0) { shA[wave] = s; shB[wave] = s2; }
  __syncthreads();
  float S = shA[0] + shA[1] + shA[2] + shA[3];
  float S2 = shB[0] + shB[1] + shB[2] + shB[3];
  float mu = S / 1024.f;
  float var = S2 / 1024.f - mu * mu;
  float inv = rsqrtf(var + 1e-6f);
  f32x4 gg = ((const f32x4*)g)[tid];
  f32x4 bv = ((const f32x4*)bb)[tid];
  f32x4 kv = ((const f32x4*)kw)[tid];
  float p = ((v.x - mu) * inv * gg.x + bv.x) * kv.x +
            ((v.y - mu) * inv * gg.y + bv.y) * kv.y +
            ((v.z - mu) * inv * gg.z + bv.z) * kv.z +
            ((v.w - mu) * inv * gg.w + bv.w) * kv.w;
#pragma unroll
  for (int off = 32; off; off >>= 1) p += __shfl_xor(p, off);
  __syncthreads();
  if (lane == 0) shA[wave] = p;
  __syncthreads();
  if (tid == 0) {
    float P = shA[0] + shA[1] + shA[2] + shA[3] + kb[0];
    score[row] = 1.f / (1.f + __expf(-P));
  }
}

// ---------------------------------------------------------------------------
extern "C" void kernel_launch(void* const* d_in, const int* in_sizes, int n_in,
                              void* d_out, int out_size, void* d_ws, size_t ws_size,
                              hipStream_t stream) {
  const float* x = (const float*)d_in[0];
  const float* xa = (const float*)d_in[1];
  const float* Wk_v = (const float*)d_in[4];
  const float* Wq_v = (const float*)d_in[5];
  const float* Wv_v = (const float*)d_in[6];
  const float* Wo_v = (const float*)d_in[7];
  const float* Wk_a = (const float*)d_in[8];
  const float* Wq_a = (const float*)d_in[9];
  const float* Wv_a = (const float*)d_in[10];
  const float* Wo_a = (const float*)d_in[11];
  const float* ka_w = (const float*)d_in[12];
  const float* ka_b = (const float*)d_in[13];
  const float* kd_w = (const float*)d_in[14];
  const float* kd_b = (const float*)d_in[15];
  const float* ln_y_g = (const float*)d_in[16];
  const float* ln_y_b = (const float*)d_in[17];
  const float* ln_ya_g = (const float*)d_in[18];
  const float* ln_ya_b = (const float*)d_in[19];
  const float* ln_ka_g = (const float*)d_in[20];
  const float* ln_ka_b = (const float*)d_in[21];

  const int N = in_sizes[0] / 1024;  // 6144
  const int MV = 1024, MA = 128, MH = 1152;

  char* wsb = (char*)d_ws;
  size_t off = 0;
  auto alloc = [&](size_t bytes) -> void* {
    void* p = wsb + off;
    off += (bytes + 255) & ~(size_t)255;
    return p;
  };
  u16* xf_b    = (u16*)alloc((size_t)N * MV * 2);
  u16* xa_b    = (u16*)alloc((size_t)N * MA * 2);
  u16* wqkv_b  = (u16*)alloc((size_t)3 * MV * MV * 2);
  u16* wqkva_b = (u16*)alloc((size_t)3 * MA * MA * 2);
  u16* wov_b   = (u16*)alloc((size_t)MV * MV * 2);
  u16* woa_b   = (u16*)alloc((size_t)MA * MA * 2);
  u16* kaw_b   = (u16*)alloc((size_t)1024 * MH * 2);
  float* QKVv  = (float*)alloc((size_t)N * 3 * MV * 4);  // cols: K|Q|V
  float* QKVa  = (float*)alloc((size_t)N * 3 * MA * 4);
  float* bandV = (float*)alloc((size_t)N * 40 * 4);
  float* bandA = (float*)alloc((size_t)N * 40 * 4);
  u16* yv_b = (u16*)alloc((size_t)N * MV * 2);
  u16* ya_b = (u16*)alloc((size_t)N * MA * 2);
  float* ov = (float*)alloc((size_t)N * MV * 4);  // reused as h after LN
  float* oa = (float*)alloc((size_t)N * MA * 4);
  u16* ycomb_b = (u16*)alloc((size_t)N * MH * 2);
  float* h = ov;

  float* dout = (float*)d_out;
  float* attBase = dout + N;

  // 1) single fused cast pass
  {
    CastTab t;
    int c = 0, cum = 0;
    auto seg = [&](const float* s, u16* d, size_t n) {
      t.src[c] = s; t.dst[c] = d; t.start[c] = cum; cum += (int)(n / 4); ++c;
    };
    seg(x, xf_b, (size_t)N * MV);
    seg(xa, xa_b, (size_t)N * MA);
    seg(Wk_v, wqkv_b + 0 * MV * MV, (size_t)MV * MV);
    seg(Wq_v, wqkv_b + 1 * MV * MV, (size_t)MV * MV);
    seg(Wv_v, wqkv_b + 2 * MV * MV, (size_t)MV * MV);
    seg(Wk_a, wqkva_b + 0 * MA * MA, (size_t)MA * MA);
    seg(Wq_a, wqkva_b + 1 * MA * MA, (size_t)MA * MA);
    seg(Wv_a, wqkva_b + 2 * MA * MA, (size_t)MA * MA);
    seg(Wo_v, wov_b, (size_t)MV * MV);
    seg(Wo_a, woa_b, (size_t)MA * MA);
    seg(ka_w, kaw_b, (size_t)1024 * MH);
    t.start[c] = cum;
    vas_cast<<<(cum + 255) / 256, 256, 0, stream>>>(t, cum);
  }

  // 2) fused QKV projections
  dim3 gv(N / 128, 3 * MV / 128);
  dim3 ga(N / 128, 3 * MA / 128);
  vas_gemm<<<gv, 256, 0, stream>>>(xf_b, wqkv_b, QKVv, nullptr, N, 3 * MV, MV, 0);
  vas_gemm<<<ga, 256, 0, stream>>>(xa_b, wqkva_b, QKVa, nullptr, N, 3 * MA, MA, 0);

  // 3) banded softmax -> band buffers
  vas_battn<1024><<<N / 4, 256, 0, stream>>>(QKVv, 3 * MV, MV, 0, bandV, N, 0.06f);
  vas_battn<128><<<N / 4, 256, 0, stream>>>(QKVa, 3 * MA, MA, 0, bandA, N, 0.06f);

  // 4) materialize att_comb (replaces memset + scatter; writes all 2N cols)
  vas_write_att<<<N, 256, 0, stream>>>(bandV, bandA, attBase, N);

  // 5) y = att.T @ V
  vas_apply_v<<<N, 256, 0, stream>>>(QKVv, 3 * MV, 2 * MV, bandV, yv_b, N);
  vas_apply_a<<<N / 4, 256, 0, stream>>>(QKVa, 3 * MA, 2 * MA, bandA, ya_b, N);

  // 6) output projections
  dim3 gov(N / 128, MV / 128);
  dim3 goa(N / 128, MA / 128);
  vas_gemm<<<gov, 256, 0, stream>>>(yv_b, wov_b, ov, nullptr, N, MV, MV, 0);
  vas_gemm<<<goa, 256, 0, stream>>>(ya_b, woa_b, oa, nullptr, N, MA, MA, 0);

  // 7) LN(o + x) -> ycomb bf16
  vas_ln_v<<<N, 256, 0, stream>>>(ov, x, ln_y_g, ln_y_b, ycomb_b, MH, 0);
  vas_ln_a<<<N, 128, 0, stream>>>(oa, xa, ln_ya_g, ln_ya_b, ycomb_b, MH, 1024);

  // 8) h = relu(ycomb @ ka_w.T + ka_b)
  dim3 gh(N / 128, 1024 / 128);
  vas_gemm<<<gh, 256, 0, stream>>>(ycomb_b, kaw_b, h, ka_b, N, 1024, MH, 1);

  // 9) score
  vas_head<<<N, 256, 0, stream>>>(h, ln_ka_g, ln_ka_b, kd_w, kd_b, dout);
}

// Round 4
// 687.554 us; speedup vs baseline: 1.1389x; 1.1389x over previous
//
#include <hip/hip_runtime.h>
#include <stdint.h>

typedef unsigned short u16;
typedef unsigned int u32;
typedef __attribute__((ext_vector_type(8))) short bf16x8;
typedef __attribute__((ext_vector_type(4))) short s16x4;
typedef __attribute__((ext_vector_type(4))) float f32x4;
typedef __attribute__((ext_vector_type(2))) float f32x2;

#define DEV __device__ __forceinline__

DEV u16 f2bf(float f) {
  union { float f; unsigned u; } v; v.f = f;
  unsigned r = v.u + 0x7fffu + ((v.u >> 16) & 1u);
  return (u16)(r >> 16);
}
DEV float bf2f(u16 h) {
  union { u32 u; float f; } v; v.u = ((u32)h) << 16; return v.f;
}
DEV int imax(int a, int b) { return a > b ? a : b; }
DEV int imin(int a, int b) { return a < b ? a : b; }

DEV void g2lds16(const u16* g, u16* l) {
  __builtin_amdgcn_global_load_lds(
      (const __attribute__((address_space(1))) void*)g,
      (__attribute__((address_space(3))) void*)l, 16, 0, 0);
}

// ---------------------------------------------------------------------------
// one-shot multi-segment f32 -> bf16 cast
// ---------------------------------------------------------------------------
#define NSEG 11
struct CastTab {
  const float* src[NSEG];
  u16* dst[NSEG];
  int start[NSEG + 1];
};

__global__ __launch_bounds__(256) void vas_cast(CastTab t, int total4) {
  int idx = blockIdx.x * 256 + threadIdx.x;
  if (idx >= total4) return;
  int s = 0;
#pragma unroll
  for (int k = 1; k < NSEG; ++k)
    if (idx >= t.start[k]) s = k;
  int local = idx - t.start[s];
  f32x4 f = ((const f32x4*)t.src[s])[local];
  s16x4 o;
  o.x = (short)f2bf(f.x);
  o.y = (short)f2bf(f.y);
  o.z = (short)f2bf(f.z);
  o.w = (short)f2bf(f.w);
  ((s16x4*)t.dst[s])[local] = o;
}

// ---------------------------------------------------------------------------
// bf16 GEMM, m97 structure + group-m swizzle for L2 locality.
// mode 0: C f32 = acc ; mode 1: C bf16 = relu(acc + bias)
// grid.x = (M/128)*(Nn/128)
// ---------------------------------------------------------------------------
__global__ __launch_bounds__(256) void vas_gemm(
    const u16* __restrict__ A, const u16* __restrict__ W,
    void* __restrict__ Cout, const float* __restrict__ bias,
    int M, int Nn, int K, int mode) {
  __shared__ u16 As[128 * 32];
  __shared__ u16 Ws[128 * 32];
  const int tid = threadIdx.x;
  const int lane = tid & 63;
  const int wave = tid >> 6;

  // group-m swizzle: GM m-blocks share their W-panel through L2
  const int Mb = M >> 7, Nb = Nn >> 7;
  const int GM = 8;
  int per = GM * Nb;
  int g = blockIdx.x / per;
  int rem = blockIdx.x - g * per;
  int gm = imin(GM, Mb - g * GM);
  int mblk = g * GM + rem % gm;
  int nblk = rem / gm;
  const int m0 = mblk * 128;
  const int n0 = nblk * 128;
  const int wm = (wave >> 1) * 64;
  const int wn = (wave & 1) * 64;

  f32x4 acc[4][4] = {};

  for (int k0 = 0; k0 < K; k0 += 32) {
#pragma unroll
    for (int hh = 0; hh < 2; ++hh) {
      int c = tid + hh * 256;
      int row = c >> 2, part = c & 3;
      g2lds16(A + (size_t)(m0 + row) * K + (k0 + part * 8), As + c * 8);
      g2lds16(W + (size_t)(n0 + row) * K + (k0 + part * 8), Ws + c * 8);
    }
    __syncthreads();
    bf16x8 af[4], bfr[4];
#pragma unroll
    for (int t = 0; t < 4; ++t)
      af[t] = *(const bf16x8*)(As + (wm + t * 16 + (lane & 15)) * 32 + (lane >> 4) * 8);
#pragma unroll
    for (int t = 0; t < 4; ++t)
      bfr[t] = *(const bf16x8*)(Ws + (wn + t * 16 + (lane & 15)) * 32 + (lane >> 4) * 8);
#pragma unroll
    for (int mi = 0; mi < 4; ++mi)
#pragma unroll
      for (int ni = 0; ni < 4; ++ni)
        acc[mi][ni] = __builtin_amdgcn_mfma_f32_16x16x32_bf16(af[mi], bfr[ni], acc[mi][ni], 0, 0, 0);
    __syncthreads();
  }

#pragma unroll
  for (int mi = 0; mi < 4; ++mi) {
#pragma unroll
    for (int ni = 0; ni < 4; ++ni) {
      int col = n0 + wn + ni * 16 + (lane & 15);
      float bv = bias ? bias[col] : 0.f;
#pragma unroll
      for (int r = 0; r < 4; ++r) {
        int row = m0 + wm + mi * 16 + (lane >> 4) * 4 + r;
        float vv = acc[mi][ni][r] + bv;
        if (mode == 0) {
          ((float*)Cout)[(size_t)row * Nn + col] = vv;
        } else {
          ((u16*)Cout)[(size_t)row * Nn + col] = f2bf(fmaxf(vv, 0.f));
        }
      }
    }
  }
}

// ---------------------------------------------------------------------------
// Banded attention softmax. MODE 0 (video): also writes the FULL att_comb row
// (zeros + band). MODE 1 (audio): scatter-writes only its band at colOff.
// One wave per row, 4 rows/block.
// ---------------------------------------------------------------------------
template <int DIM, int MODE>
__global__ __launch_bounds__(256) void vas_battn(
    const float* __restrict__ QKV, int ld, int qoff, int koff,
    float* __restrict__ band, float* __restrict__ attBase,
    int N, int colOff, float scale) {
  const int lane = threadIdx.x & 63;
  const int wave = threadIdx.x >> 6;
  const int i = blockIdx.x * 4 + wave;
  const int lo = imax(i - 19, 0);
  const int hi = imin(i + 19, N - 1);
  const int nj = hi - lo + 1;
  constexpr int C4 = DIM / 256;
  float logit = 0.f;
  __shared__ float a_sh[4][40];

  if constexpr (C4 > 0) {
    f32x4 q[C4];
    const float* qrow = QKV + (size_t)i * ld + qoff;
#pragma unroll
    for (int c = 0; c < C4; ++c) q[c] = *(const f32x4*)(qrow + c * 256 + lane * 4);
#pragma unroll 2
    for (int s = 0; s < nj; ++s) {
      const float* kr = QKV + (size_t)(lo + s) * ld + koff;
      float p = 0.f;
#pragma unroll
      for (int c = 0; c < C4; ++c) {
        f32x4 k = *(const f32x4*)(kr + c * 256 + lane * 4);
        p += q[c].x * k.x + q[c].y * k.y + q[c].z * k.z + q[c].w * k.w;
      }
#pragma unroll
      for (int off = 32; off; off >>= 1) p += __shfl_xor(p, off);
      if (lane == s) logit = p;
    }
  } else {
    f32x2 q = *(const f32x2*)(QKV + (size_t)i * ld + qoff + lane * 2);
#pragma unroll 2
    for (int s = 0; s < nj; ++s) {
      f32x2 k = *(const f32x2*)(QKV + (size_t)(lo + s) * ld + koff + lane * 2);
      float p = q.x * k.x + q.y * k.y;
#pragma unroll
      for (int off = 32; off; off >>= 1) p += __shfl_xor(p, off);
      if (lane == s) logit = p;
    }
  }

  logit *= scale;
  float v = (lane < nj) ? logit : -3.4e38f;
  float mx = v;
#pragma unroll
  for (int off = 32; off; off >>= 1) mx = fmaxf(mx, __shfl_xor(mx, off));
  float e = (lane < nj) ? __expf(v - mx) : 0.f;
  float den = e;
#pragma unroll
  for (int off = 32; off; off >>= 1) den += __shfl_xor(den, off);
  float att = (lane < nj) ? e / den : 0.f;
  if (lane < 40) {
    band[i * 40 + lane] = att;
    a_sh[wave][lane] = att;  // wave-synchronous: same wave reads below
  }

  if constexpr (MODE == 0) {
    // write the full att_comb row: zeros everywhere, band values in [lo,hi]
    f32x4* rowp = (f32x4*)(attBase + (size_t)i * 2 * N);
    const int nchunks = (2 * N) / 4;
    const int cLo = lo >> 2, cHi = hi >> 2;
    for (int c = lane; c < nchunks; c += 64) {
      f32x4 o = {0.f, 0.f, 0.f, 0.f};
      if (c >= cLo && c <= cHi) {
        int col0 = c * 4;
#pragma unroll
        for (int e2 = 0; e2 < 4; ++e2) {
          int col = col0 + e2;
          if (col >= lo && col <= hi) o[e2] = a_sh[wave][col - lo];
        }
      }
      rowp[c] = o;
    }
  } else {
    if (lane < nj)
      attBase[(size_t)i * 2 * N + colOff + lo + lane] = att;
  }
}

// ---------------------------------------------------------------------------
// y[j,:] = sum_i att[i,j] * V[i,:] (att.T @ V), band only. bf16 out.
// ---------------------------------------------------------------------------
__global__ __launch_bounds__(256) void vas_apply_v(
    const float* __restrict__ QKV, int ld, int voff,
    const float* __restrict__ band, u16* __restrict__ Y, int N) {
  const int j = blockIdx.x;
  const int tid = threadIdx.x;
  __shared__ float a_sh[40];
  const int lo = imax(j - 19, 0);
  const int hi = imin(j + 19, N - 1);
  const int ni = hi - lo + 1;
  if (tid < ni) {
    int i = lo + tid;
    a_sh[tid] = band[i * 40 + (j - imax(i - 19, 0))];
  }
  __syncthreads();
  f32x4 acc = {0.f, 0.f, 0.f, 0.f};
#pragma unroll 4
  for (int s = 0; s < ni; ++s) {
    float a = a_sh[s];
    f32x4 vv = *(const f32x4*)(QKV + (size_t)(lo + s) * ld + voff + tid * 4);
    acc.x += a * vv.x;
    acc.y += a * vv.y;
    acc.z += a * vv.z;
    acc.w += a * vv.w;
  }
  s16x4 o;
  o.x = (short)f2bf(acc.x);
  o.y = (short)f2bf(acc.y);
  o.z = (short)f2bf(acc.z);
  o.w = (short)f2bf(acc.w);
  *(s16x4*)(Y + (size_t)j * 1024 + tid * 4) = o;
}

__global__ __launch_bounds__(256) void vas_apply_a(
    const float* __restrict__ QKV, int ld, int voff,
    const float* __restrict__ band, u16* __restrict__ Y, int N) {
  const int lane = threadIdx.x & 63;
  const int wave = threadIdx.x >> 6;
  const int j = blockIdx.x * 4 + wave;
  __shared__ float a_sh[4][40];
  const int lo = imax(j - 19, 0);
  const int hi = imin(j + 19, N - 1);
  const int ni = hi - lo + 1;
  if (lane < ni) {
    int i = lo + lane;
    a_sh[wave][lane] = band[i * 40 + (j - imax(i - 19, 0))];
  }
  __syncthreads();
  f32x2 acc = {0.f, 0.f};
#pragma unroll 4
  for (int s = 0; s < ni; ++s) {
    float a = a_sh[wave][s];
    f32x2 vv = *(const f32x2*)(QKV + (size_t)(lo + s) * ld + voff + lane * 2);
    acc.x += a * vv.x;
    acc.y += a * vv.y;
  }
  u32 o = (u32)f2bf(acc.x) | ((u32)f2bf(acc.y) << 16);
  *(u32*)(Y + (size_t)j * 128 + lane * 2) = o;
}

// ---------------------------------------------------------------------------
// LayerNorm(O + X)*g + b -> bf16
// ---------------------------------------------------------------------------
__global__ __launch_bounds__(256) void vas_ln_v(
    const float* __restrict__ O, const float* __restrict__ X,
    const float* __restrict__ g, const float* __restrict__ bb,
    u16* __restrict__ out, int outStride, int outOff) {
  const int row = blockIdx.x;
  const int tid = threadIdx.x, lane = tid & 63, wave = tid >> 6;
  __shared__ float shA[4], shB[4];
  f32x4 o4 = ((const f32x4*)(O + (size_t)row * 1024))[tid];
  f32x4 x4 = ((const f32x4*)(X + (size_t)row * 1024))[tid];
  f32x4 v;
  v.x = o4.x + x4.x; v.y = o4.y + x4.y; v.z = o4.z + x4.z; v.w = o4.w + x4.w;
  float s = v.x + v.y + v.z + v.w;
  float s2 = v.x * v.x + v.y * v.y + v.z * v.z + v.w * v.w;
#pragma unroll
  for (int off = 32; off; off >>= 1) {
    s += __shfl_xor(s, off);
    s2 += __shfl_xor(s2, off);
  }
  if (lane == 0) { shA[wave] = s; shB[wave] = s2; }
  __syncthreads();
  float S = shA[0] + shA[1] + shA[2] + shA[3];
  float S2 = shB[0] + shB[1] + shB[2] + shB[3];
  float mu = S / 1024.f;
  float var = S2 / 1024.f - mu * mu;
  float inv = rsqrtf(var + 1e-6f);
  f32x4 gg = ((const f32x4*)g)[tid];
  f32x4 bv = ((const f32x4*)bb)[tid];
  s16x4 o;
  o.x = (short)f2bf((v.x - mu) * inv * gg.x + bv.x);
  o.y = (short)f2bf((v.y - mu) * inv * gg.y + bv.y);
  o.z = (short)f2bf((v.z - mu) * inv * gg.z + bv.z);
  o.w = (short)f2bf((v.w - mu) * inv * gg.w + bv.w);
  *(s16x4*)(out + (size_t)row * outStride + outOff + tid * 4) = o;
}

__global__ __launch_bounds__(128) void vas_ln_a(
    const float* __restrict__ O, const float* __restrict__ X,
    const float* __restrict__ g, const float* __restrict__ bb,
    u16* __restrict__ out, int outStride, int outOff) {
  const int row = blockIdx.x;
  const int tid = threadIdx.x, lane = tid & 63, wave = tid >> 6;
  __shared__ float shA[2], shB[2];
  float v = O[(size_t)row * 128 + tid] + X[(size_t)row * 128 + tid];
  float s = v, s2 = v * v;
#pragma unroll
  for (int off = 32; off; off >>= 1) {
    s += __shfl_xor(s, off);
    s2 += __shfl_xor(s2, off);
  }
  if (lane == 0) { shA[wave] = s; shB[wave] = s2; }
  __syncthreads();
  float S = shA[0] + shA[1];
  float S2 = shB[0] + shB[1];
  float mu = S / 128.f;
  float var = S2 / 128.f - mu * mu;
  float inv = rsqrtf(var + 1e-6f);
  out[(size_t)row * outStride + outOff + tid] = f2bf((v - mu) * inv * g[tid] + bb[tid]);
}

// ---------------------------------------------------------------------------
// head: score[row] = sigmoid( LN(H[row]) . kw + kb ), H bf16
// ---------------------------------------------------------------------------
__global__ __launch_bounds__(256) void vas_head(
    const u16* __restrict__ H, const float* __restrict__ g,
    const float* __restrict__ bb, const float* __restrict__ kw,
    const float* __restrict__ kb, float* __restrict__ score) {
  const int row = blockIdx.x;
  const int tid = threadIdx.x, lane = tid & 63, wave = tid >> 6;
  __shared__ float shA[4], shB[4];
  s16x4 raw = ((const s16x4*)(H + (size_t)row * 1024))[tid];
  f32x4 v;
  v.x = bf2f((u16)raw.x);
  v.y = bf2f((u16)raw.y);
  v.z = bf2f((u16)raw.z);
  v.w = bf2f((u16)raw.w);
  float s = v.x + v.y + v.z + v.w;
  float s2 = v.x * v.x + v.y * v.y + v.z * v.z + v.w * v.w;
#pragma unroll
  for (int off = 32; off; off >>= 1) {
    s += __shfl_xor(s, off);
    s2 += __shfl_xor(s2, off);
  }
  if (lane == 0) { shA[wave] = s; shB[wave] = s2; }
  __syncthreads();
  float S = shA[0] + shA[1] + shA[2] + shA[3];
  float S2 = shB[0] + shB[1] + shB[2] + shB[3];
  float mu = S / 1024.f;
  float var = S2 / 1024.f - mu * mu;
  float inv = rsqrtf(var + 1e-6f);
  f32x4 gg = ((const f32x4*)g)[tid];
  f32x4 bv = ((const f32x4*)bb)[tid];
  f32x4 kv = ((const f32x4*)kw)[tid];
  float p = ((v.x - mu) * inv * gg.x + bv.x) * kv.x +
            ((v.y - mu) * inv * gg.y + bv.y) * kv.y +
            ((v.z - mu) * inv * gg.z + bv.z) * kv.z +
            ((v.w - mu) * inv * gg.w + bv.w) * kv.w;
#pragma unroll
  for (int off = 32; off; off >>= 1) p += __shfl_xor(p, off);
  __syncthreads();
  if (lane == 0) shA[wave] = p;
  __syncthreads();
  if (tid == 0) {
    float P = shA[0] + shA[1] + shA[2] + shA[3] + kb[0];
    score[row] = 1.f / (1.f + __expf(-P));
  }
}

// ---------------------------------------------------------------------------
extern "C" void kernel_launch(void* const* d_in, const int* in_sizes, int n_in,
                              void* d_out, int out_size, void* d_ws, size_t ws_size,
                              hipStream_t stream) {
  const float* x = (const float*)d_in[0];
  const float* xa = (const float*)d_in[1];
  const float* Wk_v = (const float*)d_in[4];
  const float* Wq_v = (const float*)d_in[5];
  const float* Wv_v = (const float*)d_in[6];
  const float* Wo_v = (const float*)d_in[7];
  const float* Wk_a = (const float*)d_in[8];
  const float* Wq_a = (const float*)d_in[9];
  const float* Wv_a = (const float*)d_in[10];
  const float* Wo_a = (const float*)d_in[11];
  const float* ka_w = (const float*)d_in[12];
  const float* ka_b = (const float*)d_in[13];
  const float* kd_w = (const float*)d_in[14];
  const float* kd_b = (const float*)d_in[15];
  const float* ln_y_g = (const float*)d_in[16];
  const float* ln_y_b = (const float*)d_in[17];
  const float* ln_ya_g = (const float*)d_in[18];
  const float* ln_ya_b = (const float*)d_in[19];
  const float* ln_ka_g = (const float*)d_in[20];
  const float* ln_ka_b = (const float*)d_in[21];

  const int N = in_sizes[0] / 1024;  // 6144
  const int MV = 1024, MA = 128, MH = 1152;

  char* wsb = (char*)d_ws;
  size_t off = 0;
  auto alloc = [&](size_t bytes) -> void* {
    void* p = wsb + off;
    off += (bytes + 255) & ~(size_t)255;
    return p;
  };
  u16* xf_b    = (u16*)alloc((size_t)N * MV * 2);
  u16* xa_b    = (u16*)alloc((size_t)N * MA * 2);
  u16* wqkv_b  = (u16*)alloc((size_t)3 * MV * MV * 2);
  u16* wqkva_b = (u16*)alloc((size_t)3 * MA * MA * 2);
  u16* wov_b   = (u16*)alloc((size_t)MV * MV * 2);
  u16* woa_b   = (u16*)alloc((size_t)MA * MA * 2);
  u16* kaw_b   = (u16*)alloc((size_t)1024 * MH * 2);
  float* QKVv  = (float*)alloc((size_t)N * 3 * MV * 4);  // cols: K|Q|V
  float* QKVa  = (float*)alloc((size_t)N * 3 * MA * 4);
  float* bandV = (float*)alloc((size_t)N * 40 * 4);
  float* bandA = (float*)alloc((size_t)N * 40 * 4);
  u16* yv_b = (u16*)alloc((size_t)N * MV * 2);
  u16* ya_b = (u16*)alloc((size_t)N * MA * 2);
  float* ov = (float*)alloc((size_t)N * MV * 4);
  float* oa = (float*)alloc((size_t)N * MA * 4);
  u16* ycomb_b = (u16*)alloc((size_t)N * MH * 2);
  u16* h_b = (u16*)alloc((size_t)N * 1024 * 2);

  float* dout = (float*)d_out;
  float* attBase = dout + N;

  // 1) fused cast pass
  {
    CastTab t;
    int c = 0, cum = 0;
    auto seg = [&](const float* s, u16* d, size_t n) {
      t.src[c] = s; t.dst[c] = d; t.start[c] = cum; cum += (int)(n / 4); ++c;
    };
    seg(x, xf_b, (size_t)N * MV);
    seg(xa, xa_b, (size_t)N * MA);
    seg(Wk_v, wqkv_b + 0 * MV * MV, (size_t)MV * MV);
    seg(Wq_v, wqkv_b + 1 * MV * MV, (size_t)MV * MV);
    seg(Wv_v, wqkv_b + 2 * MV * MV, (size_t)MV * MV);
    seg(Wk_a, wqkva_b + 0 * MA * MA, (size_t)MA * MA);
    seg(Wq_a, wqkva_b + 1 * MA * MA, (size_t)MA * MA);
    seg(Wv_a, wqkva_b + 2 * MA * MA, (size_t)MA * MA);
    seg(Wo_v, wov_b, (size_t)MV * MV);
    seg(Wo_a, woa_b, (size_t)MA * MA);
    seg(ka_w, kaw_b, (size_t)1024 * MH);
    t.start[c] = cum;
    vas_cast<<<(cum + 255) / 256, 256, 0, stream>>>(t, cum);
  }

  // 2) fused QKV projections (grid = Mb*Nb flat, group-m swizzled)
  vas_gemm<<<(N / 128) * (3 * MV / 128), 256, 0, stream>>>(
      xf_b, wqkv_b, QKVv, nullptr, N, 3 * MV, MV, 0);
  vas_gemm<<<(N / 128) * (3 * MA / 128), 256, 0, stream>>>(
      xa_b, wqkva_b, QKVa, nullptr, N, 3 * MA, MA, 0);

  // 3) banded softmax; video also materializes full att rows, audio scatters
  vas_battn<1024, 0><<<N / 4, 256, 0, stream>>>(QKVv, 3 * MV, MV, 0, bandV, attBase, N, 0, 0.06f);
  vas_battn<128, 1><<<N / 4, 256, 0, stream>>>(QKVa, 3 * MA, MA, 0, bandA, attBase, N, N, 0.06f);

  // 4) y = att.T @ V
  vas_apply_v<<<N, 256, 0, stream>>>(QKVv, 3 * MV, 2 * MV, bandV, yv_b, N);
  vas_apply_a<<<N / 4, 256, 0, stream>>>(QKVa, 3 * MA, 2 * MA, bandA, ya_b, N);

  // 5) output projections
  vas_gemm<<<(N / 128) * (MV / 128), 256, 0, stream>>>(yv_b, wov_b, ov, nullptr, N, MV, MV, 0);
  vas_gemm<<<(N / 128) * (MA / 128), 256, 0, stream>>>(ya_b, woa_b, oa, nullptr, N, MA, MA, 0);

  // 6) LN(o + x) -> ycomb bf16
  vas_ln_v<<<N, 256, 0, stream>>>(ov, x, ln_y_g, ln_y_b, ycomb_b, MH, 0);
  vas_ln_a<<<N, 128, 0, stream>>>(oa, xa, ln_ya_g, ln_ya_b, ycomb_b, MH, 1024);

  // 7) h = relu(ycomb @ ka_w.T + ka_b), bf16 out
  vas_gemm<<<(N / 128) * (1024 / 128), 256, 0, stream>>>(
      ycomb_b, kaw_b, h_b, ka_b, N, 1024, MH, 1);

  // 8) score
  vas_head<<<N, 256, 0, stream>>>(h_b, ln_ka_g, ln_ka_b, kd_w, kd_b, dout);
}

// Round 5
// 665.076 us; speedup vs baseline: 1.1774x; 1.0338x over previous
//
#include <hip/hip_runtime.h>
#include <stdint.h>

typedef unsigned short u16;
typedef unsigned int u32;
typedef __attribute__((ext_vector_type(8))) short bf16x8;
typedef __attribute__((ext_vector_type(4))) short s16x4;
typedef __attribute__((ext_vector_type(4))) float f32x4;
typedef __attribute__((ext_vector_type(2))) float f32x2;

#define DEV __device__ __forceinline__

DEV u16 f2bf(float f) {
  union { float f; unsigned u; } v; v.f = f;
  unsigned r = v.u + 0x7fffu + ((v.u >> 16) & 1u);
  return (u16)(r >> 16);
}
DEV float bf2f(u16 h) {
  union { u32 u; float f; } v; v.u = ((u32)h) << 16; return v.f;
}
DEV int imax(int a, int b) { return a > b ? a : b; }
DEV int imin(int a, int b) { return a < b ? a : b; }

DEV void g2lds16(const u16* g, u16* l) {
  __builtin_amdgcn_global_load_lds(
      (const __attribute__((address_space(1))) void*)g,
      (__attribute__((address_space(3))) void*)l, 16, 0, 0);
}

// ---------------------------------------------------------------------------
// one-shot multi-segment f32 -> bf16 cast
// ---------------------------------------------------------------------------
#define NSEG 11
struct CastTab {
  const float* src[NSEG];
  u16* dst[NSEG];
  int start[NSEG + 1];
};

__global__ __launch_bounds__(256) void vas_cast(CastTab t, int total4) {
  int idx = blockIdx.x * 256 + threadIdx.x;
  if (idx >= total4) return;
  int s = 0;
#pragma unroll
  for (int k = 1; k < NSEG; ++k)
    if (idx >= t.start[k]) s = k;
  int local = idx - t.start[s];
  f32x4 f = ((const f32x4*)t.src[s])[local];
  s16x4 o;
  o.x = (short)f2bf(f.x);
  o.y = (short)f2bf(f.y);
  o.z = (short)f2bf(f.z);
  o.w = (short)f2bf(f.w);
  ((s16x4*)t.dst[s])[local] = o;
}

// ---------------------------------------------------------------------------
// bf16 GEMM, m97 structure + group-m swizzle for L2 locality.
// mode 0: C f32 = acc ; mode 1: C bf16 = relu(acc + bias)
// ---------------------------------------------------------------------------
__global__ __launch_bounds__(256) void vas_gemm(
    const u16* __restrict__ A, const u16* __restrict__ W,
    void* __restrict__ Cout, const float* __restrict__ bias,
    int M, int Nn, int K, int mode) {
  __shared__ u16 As[128 * 32];
  __shared__ u16 Ws[128 * 32];
  const int tid = threadIdx.x;
  const int lane = tid & 63;
  const int wave = tid >> 6;

  const int Mb = M >> 7, Nb = Nn >> 7;
  const int GM = 8;
  int per = GM * Nb;
  int g = blockIdx.x / per;
  int rem = blockIdx.x - g * per;
  int gm = imin(GM, Mb - g * GM);
  int mblk = g * GM + rem % gm;
  int nblk = rem / gm;
  const int m0 = mblk * 128;
  const int n0 = nblk * 128;
  const int wm = (wave >> 1) * 64;
  const int wn = (wave & 1) * 64;

  f32x4 acc[4][4] = {};

  for (int k0 = 0; k0 < K; k0 += 32) {
#pragma unroll
    for (int hh = 0; hh < 2; ++hh) {
      int c = tid + hh * 256;
      int row = c >> 2, part = c & 3;
      g2lds16(A + (size_t)(m0 + row) * K + (k0 + part * 8), As + c * 8);
      g2lds16(W + (size_t)(n0 + row) * K + (k0 + part * 8), Ws + c * 8);
    }
    __syncthreads();
    bf16x8 af[4], bfr[4];
#pragma unroll
    for (int t = 0; t < 4; ++t)
      af[t] = *(const bf16x8*)(As + (wm + t * 16 + (lane & 15)) * 32 + (lane >> 4) * 8);
#pragma unroll
    for (int t = 0; t < 4; ++t)
      bfr[t] = *(const bf16x8*)(Ws + (wn + t * 16 + (lane & 15)) * 32 + (lane >> 4) * 8);
#pragma unroll
    for (int mi = 0; mi < 4; ++mi)
#pragma unroll
      for (int ni = 0; ni < 4; ++ni)
        acc[mi][ni] = __builtin_amdgcn_mfma_f32_16x16x32_bf16(af[mi], bfr[ni], acc[mi][ni], 0, 0, 0);
    __syncthreads();
  }

#pragma unroll
  for (int mi = 0; mi < 4; ++mi) {
#pragma unroll
    for (int ni = 0; ni < 4; ++ni) {
      int col = n0 + wn + ni * 16 + (lane & 15);
      float bv = bias ? bias[col] : 0.f;
#pragma unroll
      for (int r = 0; r < 4; ++r) {
        int row = m0 + wm + mi * 16 + (lane >> 4) * 4 + r;
        float vv = acc[mi][ni][r] + bv;
        if (mode == 0) {
          ((float*)Cout)[(size_t)row * Nn + col] = vv;
        } else {
          ((u16*)Cout)[(size_t)row * Nn + col] = f2bf(fmaxf(vv, 0.f));
        }
      }
    }
  }
}

// ---------------------------------------------------------------------------
// Banded attention softmax. MODE 0 (video): also writes FULL att_comb row.
// MODE 1 (audio): scatter-writes only its band at colOff.
// ---------------------------------------------------------------------------
template <int DIM, int MODE>
__global__ __launch_bounds__(256) void vas_battn(
    const float* __restrict__ QKV, int ld, int qoff, int koff,
    float* __restrict__ band, float* __restrict__ attBase,
    int N, int colOff, float scale) {
  const int lane = threadIdx.x & 63;
  const int wave = threadIdx.x >> 6;
  const int i = blockIdx.x * 4 + wave;
  const int lo = imax(i - 19, 0);
  const int hi = imin(i + 19, N - 1);
  const int nj = hi - lo + 1;
  constexpr int C4 = DIM / 256;
  float logit = 0.f;
  __shared__ float a_sh[4][40];

  if constexpr (C4 > 0) {
    f32x4 q[C4];
    const float* qrow = QKV + (size_t)i * ld + qoff;
#pragma unroll
    for (int c = 0; c < C4; ++c) q[c] = *(const f32x4*)(qrow + c * 256 + lane * 4);
#pragma unroll 2
    for (int s = 0; s < nj; ++s) {
      const float* kr = QKV + (size_t)(lo + s) * ld + koff;
      float p = 0.f;
#pragma unroll
      for (int c = 0; c < C4; ++c) {
        f32x4 k = *(const f32x4*)(kr + c * 256 + lane * 4);
        p += q[c].x * k.x + q[c].y * k.y + q[c].z * k.z + q[c].w * k.w;
      }
#pragma unroll
      for (int off = 32; off; off >>= 1) p += __shfl_xor(p, off);
      if (lane == s) logit = p;
    }
  } else {
    f32x2 q = *(const f32x2*)(QKV + (size_t)i * ld + qoff + lane * 2);
#pragma unroll 2
    for (int s = 0; s < nj; ++s) {
      f32x2 k = *(const f32x2*)(QKV + (size_t)(lo + s) * ld + koff + lane * 2);
      float p = q.x * k.x + q.y * k.y;
#pragma unroll
      for (int off = 32; off; off >>= 1) p += __shfl_xor(p, off);
      if (lane == s) logit = p;
    }
  }

  logit *= scale;
  float v = (lane < nj) ? logit : -3.4e38f;
  float mx = v;
#pragma unroll
  for (int off = 32; off; off >>= 1) mx = fmaxf(mx, __shfl_xor(mx, off));
  float e = (lane < nj) ? __expf(v - mx) : 0.f;
  float den = e;
#pragma unroll
  for (int off = 32; off; off >>= 1) den += __shfl_xor(den, off);
  float att = (lane < nj) ? e / den : 0.f;
  if (lane < 40) {
    band[i * 40 + lane] = att;
    a_sh[wave][lane] = att;  // wave-synchronous: same wave reads below
  }

  if constexpr (MODE == 0) {
    f32x4* rowp = (f32x4*)(attBase + (size_t)i * 2 * N);
    const int nchunks = (2 * N) / 4;
    const int cLo = lo >> 2, cHi = hi >> 2;
    for (int c = lane; c < nchunks; c += 64) {
      f32x4 o = {0.f, 0.f, 0.f, 0.f};
      if (c >= cLo && c <= cHi) {
        int col0 = c * 4;
#pragma unroll
        for (int e2 = 0; e2 < 4; ++e2) {
          int col = col0 + e2;
          if (col >= lo && col <= hi) o[e2] = a_sh[wave][col - lo];
        }
      }
      rowp[c] = o;
    }
  } else {
    if (lane < nj)
      attBase[(size_t)i * 2 * N + colOff + lo + lane] = att;
  }
}

// ---------------------------------------------------------------------------
// y[j,:] = sum_i att[i,j] * V[i,:], j-tiled (JT j's per block share V rows).
// Zero-padded LDS weight table -> branch-free FMA loop. bf16 out.
// ---------------------------------------------------------------------------
#define JT 8
__global__ __launch_bounds__(256) void vas_apply_v(
    const float* __restrict__ QKV, int ld, int voff,
    const float* __restrict__ band, u16* __restrict__ Y, int N) {
  const int j0 = blockIdx.x * JT;
  const int tid = threadIdx.x;
  const int base = j0 - 19;  // global row of s=0
  __shared__ float a_sh[JT + 38][JT];

  for (int idx = tid; idx < (JT + 38) * JT; idx += 256) {
    int s = idx / JT, jj = idx % JT;
    int i = base + s;
    int j = j0 + jj;
    float w = 0.f;
    if (i >= 0 && i < N) {
      int d = j - i;
      if (d > -20 && d < 20) w = band[i * 40 + (j - imax(i - 19, 0))];
    }
    a_sh[s][jj] = w;
  }
  __syncthreads();

  f32x4 acc[JT] = {};
  const int sLo = imax(0, -base);
  const int sHi = imin(JT + 38, N - base);
  for (int s = sLo; s < sHi; ++s) {
    f32x4 vv = *(const f32x4*)(QKV + (size_t)(base + s) * ld + voff + tid * 4);
#pragma unroll
    for (int jj = 0; jj < JT; ++jj) {
      float a = a_sh[s][jj];  // broadcast read
      acc[jj].x += a * vv.x;
      acc[jj].y += a * vv.y;
      acc[jj].z += a * vv.z;
      acc[jj].w += a * vv.w;
    }
  }
#pragma unroll
  for (int jj = 0; jj < JT; ++jj) {
    s16x4 o;
    o.x = (short)f2bf(acc[jj].x);
    o.y = (short)f2bf(acc[jj].y);
    o.z = (short)f2bf(acc[jj].z);
    o.w = (short)f2bf(acc[jj].w);
    *(s16x4*)(Y + (size_t)(j0 + jj) * 1024 + tid * 4) = o;
  }
}

__global__ __launch_bounds__(256) void vas_apply_a(
    const float* __restrict__ QKV, int ld, int voff,
    const float* __restrict__ band, u16* __restrict__ Y, int N) {
  const int lane = threadIdx.x & 63;
  const int wave = threadIdx.x >> 6;
  const int j = blockIdx.x * 4 + wave;
  __shared__ float a_sh[4][40];
  const int lo = imax(j - 19, 0);
  const int hi = imin(j + 19, N - 1);
  const int ni = hi - lo + 1;
  if (lane < ni) {
    int i = lo + lane;
    a_sh[wave][lane] = band[i * 40 + (j - imax(i - 19, 0))];
  }
  __syncthreads();
  f32x2 acc = {0.f, 0.f};
#pragma unroll 4
  for (int s = 0; s < ni; ++s) {
    float a = a_sh[wave][s];
    f32x2 vv = *(const f32x2*)(QKV + (size_t)(lo + s) * ld + voff + lane * 2);
    acc.x += a * vv.x;
    acc.y += a * vv.y;
  }
  u32 o = (u32)f2bf(acc.x) | ((u32)f2bf(acc.y) << 16);
  *(u32*)(Y + (size_t)j * 128 + lane * 2) = o;
}

// ---------------------------------------------------------------------------
// Merged LayerNorm(O + X)*g + b -> bf16 into ycomb columns.
// Blocks [0,N): video rows (1024 wide). Blocks [N,2N): audio rows (128 wide).
// ---------------------------------------------------------------------------
__global__ __launch_bounds__(256) void vas_ln(
    const float* __restrict__ Ov, const float* __restrict__ Xv,
    const float* __restrict__ gv, const float* __restrict__ bv_,
    const float* __restrict__ Oa, const float* __restrict__ Xa,
    const float* __restrict__ ga, const float* __restrict__ ba,
    u16* __restrict__ out, int outStride, int N) {
  const int blk = blockIdx.x;
  const int tid = threadIdx.x, lane = tid & 63, wave = tid >> 6;
  __shared__ float shA[4], shB[4];

  if (blk < N) {
    const int row = blk;
    f32x4 o4 = ((const f32x4*)(Ov + (size_t)row * 1024))[tid];
    f32x4 x4 = ((const f32x4*)(Xv + (size_t)row * 1024))[tid];
    f32x4 v;
    v.x = o4.x + x4.x; v.y = o4.y + x4.y; v.z = o4.z + x4.z; v.w = o4.w + x4.w;
    float s = v.x + v.y + v.z + v.w;
    float s2 = v.x * v.x + v.y * v.y + v.z * v.z + v.w * v.w;
#pragma unroll
    for (int off = 32; off; off >>= 1) {
      s += __shfl_xor(s, off);
      s2 += __shfl_xor(s2, off);
    }
    if (lane == 0) { shA[wave] = s; shB[wave] = s2; }
    __syncthreads();
    float S = shA[0] + shA[1] + shA[2] + shA[3];
    float S2 = shB[0] + shB[1] + shB[2] + shB[3];
    float mu = S / 1024.f;
    float var = S2 / 1024.f - mu * mu;
    float inv = rsqrtf(var + 1e-6f);
    f32x4 gg = ((const f32x4*)gv)[tid];
    f32x4 bb = ((const f32x4*)bv_)[tid];
    s16x4 o;
    o.x = (short)f2bf((v.x - mu) * inv * gg.x + bb.x);
    o.y = (short)f2bf((v.y - mu) * inv * gg.y + bb.y);
    o.z = (short)f2bf((v.z - mu) * inv * gg.z + bb.z);
    o.w = (short)f2bf((v.w - mu) * inv * gg.w + bb.w);
    *(s16x4*)(out + (size_t)row * outStride + tid * 4) = o;
  } else {
    const int row = blk - N;
    float v = 0.f;
    if (tid < 128) v = Oa[(size_t)row * 128 + tid] + Xa[(size_t)row * 128 + tid];
    float s = v, s2 = v * v;
#pragma unroll
    for (int off = 32; off; off >>= 1) {
      s += __shfl_xor(s, off);
      s2 += __shfl_xor(s2, off);
    }
    if (lane == 0) { shA[wave] = s; shB[wave] = s2; }
    __syncthreads();
    float S = shA[0] + shA[1];
    float S2 = shB[0] + shB[1];
    float mu = S / 128.f;
    float var = S2 / 128.f - mu * mu;
    float inv = rsqrtf(var + 1e-6f);
    if (tid < 128)
      out[(size_t)row * outStride + 1024 + tid] =
          f2bf((v - mu) * inv * ga[tid] + ba[tid]);
  }
}

// ---------------------------------------------------------------------------
// head: score[row] = sigmoid( LN(H[row]) . kw + kb ), H bf16
// ---------------------------------------------------------------------------
__global__ __launch_bounds__(256) void vas_head(
    const u16* __restrict__ H, const float* __restrict__ g,
    const float* __restrict__ bb, const float* __restrict__ kw,
    const float* __restrict__ kb, float* __restrict__ score) {
  const int row = blockIdx.x;
  const int tid = threadIdx.x, lane = tid & 63, wave = tid >> 6;
  __shared__ float shA[4], shB[4];
  s16x4 raw = ((const s16x4*)(H + (size_t)row * 1024))[tid];
  f32x4 v;
  v.x = bf2f((u16)raw.x);
  v.y = bf2f((u16)raw.y);
  v.z = bf2f((u16)raw.z);
  v.w = bf2f((u16)raw.w);
  float s = v.x + v.y + v.z + v.w;
  float s2 = v.x * v.x + v.y * v.y + v.z * v.z + v.w * v.w;
#pragma unroll
  for (int off = 32; off; off >>= 1) {
    s += __shfl_xor(s, off);
    s2 += __shfl_xor(s2, off);
  }
  if (lane == 0) { shA[wave] = s; shB[wave] = s2; }
  __syncthreads();
  float S = shA[0] + shA[1] + shA[2] + shA[3];
  float S2 = shB[0] + shB[1] + shB[2] + shB[3];
  float mu = S / 1024.f;
  float var = S2 / 1024.f - mu * mu;
  float inv = rsqrtf(var + 1e-6f);
  f32x4 gg = ((const f32x4*)g)[tid];
  f32x4 bv = ((const f32x4*)bb)[tid];
  f32x4 kv = ((const f32x4*)kw)[tid];
  float p = ((v.x - mu) * inv * gg.x + bv.x) * kv.x +
            ((v.y - mu) * inv * gg.y + bv.y) * kv.y +
            ((v.z - mu) * inv * gg.z + bv.z) * kv.z +
            ((v.w - mu) * inv * gg.w + bv.w) * kv.w;
#pragma unroll
  for (int off = 32; off; off >>= 1) p += __shfl_xor(p, off);
  __syncthreads();
  if (lane == 0) shA[wave] = p;
  __syncthreads();
  if (tid == 0) {
    float P = shA[0] + shA[1] + shA[2] + shA[3] + kb[0];
    score[row] = 1.f / (1.f + __expf(-P));
  }
}

// ---------------------------------------------------------------------------
extern "C" void kernel_launch(void* const* d_in, const int* in_sizes, int n_in,
                              void* d_out, int out_size, void* d_ws, size_t ws_size,
                              hipStream_t stream) {
  const float* x = (const float*)d_in[0];
  const float* xa = (const float*)d_in[1];
  const float* Wk_v = (const float*)d_in[4];
  const float* Wq_v = (const float*)d_in[5];
  const float* Wv_v = (const float*)d_in[6];
  const float* Wo_v = (const float*)d_in[7];
  const float* Wk_a = (const float*)d_in[8];
  const float* Wq_a = (const float*)d_in[9];
  const float* Wv_a = (const float*)d_in[10];
  const float* Wo_a = (const float*)d_in[11];
  const float* ka_w = (const float*)d_in[12];
  const float* ka_b = (const float*)d_in[13];
  const float* kd_w = (const float*)d_in[14];
  const float* kd_b = (const float*)d_in[15];
  const float* ln_y_g = (const float*)d_in[16];
  const float* ln_y_b = (const float*)d_in[17];
  const float* ln_ya_g = (const float*)d_in[18];
  const float* ln_ya_b = (const float*)d_in[19];
  const float* ln_ka_g = (const float*)d_in[20];
  const float* ln_ka_b = (const float*)d_in[21];

  const int N = in_sizes[0] / 1024;  // 6144
  const int MV = 1024, MA = 128, MH = 1152;

  char* wsb = (char*)d_ws;
  size_t off = 0;
  auto alloc = [&](size_t bytes) -> void* {
    void* p = wsb + off;
    off += (bytes + 255) & ~(size_t)255;
    return p;
  };
  u16* xf_b    = (u16*)alloc((size_t)N * MV * 2);
  u16* xa_b    = (u16*)alloc((size_t)N * MA * 2);
  u16* wqkv_b  = (u16*)alloc((size_t)3 * MV * MV * 2);
  u16* wqkva_b = (u16*)alloc((size_t)3 * MA * MA * 2);
  u16* wov_b   = (u16*)alloc((size_t)MV * MV * 2);
  u16* woa_b   = (u16*)alloc((size_t)MA * MA * 2);
  u16* kaw_b   = (u16*)alloc((size_t)1024 * MH * 2);
  float* QKVv  = (float*)alloc((size_t)N * 3 * MV * 4);  // cols: K|Q|V
  float* QKVa  = (float*)alloc((size_t)N * 3 * MA * 4);
  float* bandV = (float*)alloc((size_t)N * 40 * 4);
  float* bandA = (float*)alloc((size_t)N * 40 * 4);
  u16* yv_b = (u16*)alloc((size_t)N * MV * 2);
  u16* ya_b = (u16*)alloc((size_t)N * MA * 2);
  float* ov = (float*)alloc((size_t)N * MV * 4);
  float* oa = (float*)alloc((size_t)N * MA * 4);
  u16* ycomb_b = (u16*)alloc((size_t)N * MH * 2);
  u16* h_b = (u16*)alloc((size_t)N * 1024 * 2);

  float* dout = (float*)d_out;
  float* attBase = dout + N;

  // 1) fused cast pass
  {
    CastTab t;
    int c = 0, cum = 0;
    auto seg = [&](const float* s, u16* d, size_t n) {
      t.src[c] = s; t.dst[c] = d; t.start[c] = cum; cum += (int)(n / 4); ++c;
    };
    seg(x, xf_b, (size_t)N * MV);
    seg(xa, xa_b, (size_t)N * MA);
    seg(Wk_v, wqkv_b + 0 * MV * MV, (size_t)MV * MV);
    seg(Wq_v, wqkv_b + 1 * MV * MV, (size_t)MV * MV);
    seg(Wv_v, wqkv_b + 2 * MV * MV, (size_t)MV * MV);
    seg(Wk_a, wqkva_b + 0 * MA * MA, (size_t)MA * MA);
    seg(Wq_a, wqkva_b + 1 * MA * MA, (size_t)MA * MA);
    seg(Wv_a, wqkva_b + 2 * MA * MA, (size_t)MA * MA);
    seg(Wo_v, wov_b, (size_t)MV * MV);
    seg(Wo_a, woa_b, (size_t)MA * MA);
    seg(ka_w, kaw_b, (size_t)1024 * MH);
    t.start[c] = cum;
    vas_cast<<<(cum + 255) / 256, 256, 0, stream>>>(t, cum);
  }

  // 2) fused QKV projections
  vas_gemm<<<(N / 128) * (3 * MV / 128), 256, 0, stream>>>(
      xf_b, wqkv_b, QKVv, nullptr, N, 3 * MV, MV, 0);
  vas_gemm<<<(N / 128) * (3 * MA / 128), 256, 0, stream>>>(
      xa_b, wqkva_b, QKVa, nullptr, N, 3 * MA, MA, 0);

  // 3) banded softmax; video also materializes full att rows, audio scatters
  vas_battn<1024, 0><<<N / 4, 256, 0, stream>>>(QKVv, 3 * MV, MV, 0, bandV, attBase, N, 0, 0.06f);
  vas_battn<128, 1><<<N / 4, 256, 0, stream>>>(QKVa, 3 * MA, MA, 0, bandA, attBase, N, N, 0.06f);

  // 4) y = att.T @ V (video j-tiled for V-row reuse)
  vas_apply_v<<<N / JT, 256, 0, stream>>>(QKVv, 3 * MV, 2 * MV, bandV, yv_b, N);
  vas_apply_a<<<N / 4, 256, 0, stream>>>(QKVa, 3 * MA, 2 * MA, bandA, ya_b, N);

  // 5) output projections
  vas_gemm<<<(N / 128) * (MV / 128), 256, 0, stream>>>(yv_b, wov_b, ov, nullptr, N, MV, MV, 0);
  vas_gemm<<<(N / 128) * (MA / 128), 256, 0, stream>>>(ya_b, woa_b, oa, nullptr, N, MA, MA, 0);

  // 6) merged LN(o + x) -> ycomb bf16 (video rows then audio rows)
  vas_ln<<<2 * N, 256, 0, stream>>>(ov, x, ln_y_g, ln_y_b,
                                    oa, xa, ln_ya_g, ln_ya_b,
                                    ycomb_b, MH, N);

  // 7) h = relu(ycomb @ ka_w.T + ka_b), bf16 out
  vas_gemm<<<(N / 128) * (1024 / 128), 256, 0, stream>>>(
      ycomb_b, kaw_b, h_b, ka_b, N, 1024, MH, 1);

  // 8) score
  vas_head<<<N, 256, 0, stream>>>(h_b, ln_ka_g, ln_ka_b, kd_w, kd_b, dout);
}

// Round 6
// 608.651 us; speedup vs baseline: 1.2865x; 1.0927x over previous
//
#include <hip/hip_runtime.h>
#include <stdint.h>

typedef unsigned short u16;
typedef unsigned int u32;
typedef __attribute__((ext_vector_type(8))) short bf16x8;
typedef __attribute__((ext_vector_type(4))) short s16x4;
typedef __attribute__((ext_vector_type(4))) float f32x4;
typedef __attribute__((ext_vector_type(2))) float f32x2;

#define DEV __device__ __forceinline__

DEV u16 f2bf(float f) {
  union { float f; unsigned u; } v; v.f = f;
  unsigned r = v.u + 0x7fffu + ((v.u >> 16) & 1u);
  return (u16)(r >> 16);
}
DEV float bf2f(u16 h) {
  union { u32 u; float f; } v; v.u = ((u32)h) << 16; return v.f;
}
DEV float lo16(u32 w) { union { u32 u; float f; } v; v.u = w << 16; return v.f; }
DEV float hi16(u32 w) { union { u32 u; float f; } v; v.u = w & 0xFFFF0000u; return v.f; }
DEV int imax(int a, int b) { return a > b ? a : b; }
DEV int imin(int a, int b) { return a < b ? a : b; }

DEV void g2lds16(const u16* g, u16* l) {
  __builtin_amdgcn_global_load_lds(
      (const __attribute__((address_space(1))) void*)g,
      (__attribute__((address_space(3))) void*)l, 16, 0, 0);
}

// ---------------------------------------------------------------------------
// one-shot multi-segment f32 -> bf16 cast
// ---------------------------------------------------------------------------
#define NSEG 11
struct CastTab {
  const float* src[NSEG];
  u16* dst[NSEG];
  int start[NSEG + 1];
};

__global__ __launch_bounds__(256) void vas_cast(CastTab t, int total4) {
  int idx = blockIdx.x * 256 + threadIdx.x;
  if (idx >= total4) return;
  int s = 0;
#pragma unroll
  for (int k = 1; k < NSEG; ++k)
    if (idx >= t.start[k]) s = k;
  int local = idx - t.start[s];
  f32x4 f = ((const f32x4*)t.src[s])[local];
  s16x4 o;
  o.x = (short)f2bf(f.x);
  o.y = (short)f2bf(f.y);
  o.z = (short)f2bf(f.z);
  o.w = (short)f2bf(f.w);
  ((s16x4*)t.dst[s])[local] = o;
}

// ---------------------------------------------------------------------------
// Dual bf16 GEMM: one grid runs two independent GEMMs (video part then audio
// part). m97 structure + group-m swizzle. mode 0: f32 out; 1: bf16 relu+bias;
// 2: bf16 plain.
// ---------------------------------------------------------------------------
struct GemmP {
  const u16* A;
  const u16* W;
  void* C;
  const float* bias;
  int M, Nn, K, mode;
};

__global__ __launch_bounds__(256) void vas_gemm2(GemmP p0, GemmP p1, int split) {
  const bool first = blockIdx.x < (u32)split;
  GemmP p = first ? p0 : p1;
  const int bid = first ? blockIdx.x : blockIdx.x - split;

  __shared__ u16 As[128 * 32];
  __shared__ u16 Ws[128 * 32];
  const int tid = threadIdx.x;
  const int lane = tid & 63;
  const int wave = tid >> 6;

  const int Mb = p.M >> 7, Nb = p.Nn >> 7;
  const int GM = 8;
  int per = GM * Nb;
  int g = bid / per;
  int rem = bid - g * per;
  int gm = imin(GM, Mb - g * GM);
  int mblk = g * GM + rem % gm;
  int nblk = rem / gm;
  const int m0 = mblk * 128;
  const int n0 = nblk * 128;
  const int wm = (wave >> 1) * 64;
  const int wn = (wave & 1) * 64;

  f32x4 acc[4][4] = {};

  for (int k0 = 0; k0 < p.K; k0 += 32) {
#pragma unroll
    for (int hh = 0; hh < 2; ++hh) {
      int c = tid + hh * 256;
      int row = c >> 2, part = c & 3;
      g2lds16(p.A + (size_t)(m0 + row) * p.K + (k0 + part * 8), As + c * 8);
      g2lds16(p.W + (size_t)(n0 + row) * p.K + (k0 + part * 8), Ws + c * 8);
    }
    __syncthreads();
    bf16x8 af[4], bfr[4];
#pragma unroll
    for (int t = 0; t < 4; ++t)
      af[t] = *(const bf16x8*)(As + (wm + t * 16 + (lane & 15)) * 32 + (lane >> 4) * 8);
#pragma unroll
    for (int t = 0; t < 4; ++t)
      bfr[t] = *(const bf16x8*)(Ws + (wn + t * 16 + (lane & 15)) * 32 + (lane >> 4) * 8);
#pragma unroll
    for (int mi = 0; mi < 4; ++mi)
#pragma unroll
      for (int ni = 0; ni < 4; ++ni)
        acc[mi][ni] = __builtin_amdgcn_mfma_f32_16x16x32_bf16(af[mi], bfr[ni], acc[mi][ni], 0, 0, 0);
    __syncthreads();
  }

#pragma unroll
  for (int mi = 0; mi < 4; ++mi) {
#pragma unroll
    for (int ni = 0; ni < 4; ++ni) {
      int col = n0 + wn + ni * 16 + (lane & 15);
      float bv = p.bias ? p.bias[col] : 0.f;
#pragma unroll
      for (int r = 0; r < 4; ++r) {
        int row = m0 + wm + mi * 16 + (lane >> 4) * 4 + r;
        float vv = acc[mi][ni][r] + bv;
        size_t idx = (size_t)row * p.Nn + col;
        if (p.mode == 0) ((float*)p.C)[idx] = vv;
        else if (p.mode == 1) ((u16*)p.C)[idx] = f2bf(fmaxf(vv, 0.f));
        else ((u16*)p.C)[idx] = f2bf(vv);
      }
    }
  }
}

// ---------------------------------------------------------------------------
// Fused banded attention softmax (bf16 Q/K). Blocks [0,vb): video rows -> band
// + att cols [0,N). Blocks [vb,2vb): audio rows -> band + att cols [N,2N).
// One wave per row, 4 rows/block. QKV layout cols K|Q|V.
// ---------------------------------------------------------------------------
__global__ __launch_bounds__(256) void vas_battn(
    const u16* __restrict__ QKVv, const u16* __restrict__ QKVa,
    float* __restrict__ bandV, float* __restrict__ bandA,
    float* __restrict__ attBase, int N, float scale, int vb) {
  const int lane = threadIdx.x & 63;
  const int wave = threadIdx.x >> 6;
  const bool video = blockIdx.x < (u32)vb;
  const int i = (video ? blockIdx.x : blockIdx.x - vb) * 4 + wave;
  const int lo = imax(i - 19, 0);
  const int hi = imin(i + 19, N - 1);
  const int nj = hi - lo + 1;
  float logit = 0.f;
  __shared__ float a_sh[4][40];

  if (video) {
    // 1024 dims: lane covers 2 chunks of 8 bf16 (chunk c at c*512 + lane*8)
    float qf[16];
    const u16* qrow = QKVv + (size_t)i * 3072 + 1024;
#pragma unroll
    for (int c = 0; c < 2; ++c) {
      bf16x8 qv = *(const bf16x8*)(qrow + c * 512 + lane * 8);
      const u32* qw = (const u32*)&qv;
#pragma unroll
      for (int t = 0; t < 4; ++t) {
        qf[c * 8 + 2 * t] = lo16(qw[t]);
        qf[c * 8 + 2 * t + 1] = hi16(qw[t]);
      }
    }
#pragma unroll 2
    for (int s = 0; s < nj; ++s) {
      const u16* kr = QKVv + (size_t)(lo + s) * 3072;
      float p = 0.f;
#pragma unroll
      for (int c = 0; c < 2; ++c) {
        bf16x8 kv = *(const bf16x8*)(kr + c * 512 + lane * 8);
        const u32* kw = (const u32*)&kv;
#pragma unroll
        for (int t = 0; t < 4; ++t)
          p += lo16(kw[t]) * qf[c * 8 + 2 * t] + hi16(kw[t]) * qf[c * 8 + 2 * t + 1];
      }
#pragma unroll
      for (int off = 32; off; off >>= 1) p += __shfl_xor(p, off);
      if (lane == s) logit = p;
    }
  } else {
    u32 q = *(const u32*)(QKVa + (size_t)i * 384 + 128 + lane * 2);
    float q0 = lo16(q), q1 = hi16(q);
#pragma unroll 2
    for (int s = 0; s < nj; ++s) {
      u32 k = *(const u32*)(QKVa + (size_t)(lo + s) * 384 + lane * 2);
      float p = lo16(k) * q0 + hi16(k) * q1;
#pragma unroll
      for (int off = 32; off; off >>= 1) p += __shfl_xor(p, off);
      if (lane == s) logit = p;
    }
  }

  logit *= scale;
  float v = (lane < nj) ? logit : -3.4e38f;
  float mx = v;
#pragma unroll
  for (int off = 32; off; off >>= 1) mx = fmaxf(mx, __shfl_xor(mx, off));
  float e = (lane < nj) ? __expf(v - mx) : 0.f;
  float den = e;
#pragma unroll
  for (int off = 32; off; off >>= 1) den += __shfl_xor(den, off);
  float att = (lane < nj) ? e / den : 0.f;
  float* band = video ? bandV : bandA;
  if (lane < 40) {
    band[i * 40 + lane] = att;
    a_sh[wave][lane] = att;  // wave-synchronous: same wave reads below
  }

  // write this row's half of att_comb: zeros + band
  f32x4* rowp = (f32x4*)(attBase + (size_t)i * 2 * N + (video ? 0 : N));
  const int nchunks = N / 4;
  const int cLo = lo >> 2, cHi = hi >> 2;
  for (int c = lane; c < nchunks; c += 64) {
    f32x4 o = {0.f, 0.f, 0.f, 0.f};
    if (c >= cLo && c <= cHi) {
      int col0 = c * 4;
#pragma unroll
      for (int e2 = 0; e2 < 4; ++e2) {
        int col = col0 + e2;
        if (col >= lo && col <= hi) o[e2] = a_sh[wave][col - lo];
      }
    }
    rowp[c] = o;
  }
}

// ---------------------------------------------------------------------------
// Fused apply: y[j,:] = sum_i att[i,j] * V[i,:] (att.T @ V), bf16 V, bf16 out.
// Blocks [0,vb): video, JT j's per block. Blocks [vb, vb+N/4): audio, wave/j.
// ---------------------------------------------------------------------------
#define JT 8
__global__ __launch_bounds__(256) void vas_apply(
    const u16* __restrict__ QKVv, const u16* __restrict__ QKVa,
    const float* __restrict__ bandV, const float* __restrict__ bandA,
    u16* __restrict__ Yv, u16* __restrict__ Ya, int N, int vb) {
  const int tid = threadIdx.x;
  __shared__ float a_sh[(JT + 38) * JT];  // video table; audio uses first 160

  if (blockIdx.x < (u32)vb) {
    const int j0 = blockIdx.x * JT;
    const int base = j0 - 19;
    for (int idx = tid; idx < (JT + 38) * JT; idx += 256) {
      int s = idx / JT, jj = idx % JT;
      int i = base + s;
      int j = j0 + jj;
      float w = 0.f;
      if (i >= 0 && i < N) {
        int d = j - i;
        if (d > -20 && d < 20) w = bandV[i * 40 + (j - imax(i - 19, 0))];
      }
      a_sh[s * JT + jj] = w;
    }
    __syncthreads();

    f32x4 acc[JT] = {};
    const int sLo = imax(0, -base);
    const int sHi = imin(JT + 38, N - base);
    for (int s = sLo; s < sHi; ++s) {
      s16x4 raw = *(const s16x4*)(QKVv + (size_t)(base + s) * 3072 + 2048 + tid * 4);
      f32x4 vv;
      vv.x = bf2f((u16)raw.x);
      vv.y = bf2f((u16)raw.y);
      vv.z = bf2f((u16)raw.z);
      vv.w = bf2f((u16)raw.w);
#pragma unroll
      for (int jj = 0; jj < JT; ++jj) {
        float a = a_sh[s * JT + jj];
        acc[jj].x += a * vv.x;
        acc[jj].y += a * vv.y;
        acc[jj].z += a * vv.z;
        acc[jj].w += a * vv.w;
      }
    }
#pragma unroll
    for (int jj = 0; jj < JT; ++jj) {
      s16x4 o;
      o.x = (short)f2bf(acc[jj].x);
      o.y = (short)f2bf(acc[jj].y);
      o.z = (short)f2bf(acc[jj].z);
      o.w = (short)f2bf(acc[jj].w);
      *(s16x4*)(Yv + (size_t)(j0 + jj) * 1024 + tid * 4) = o;
    }
  } else {
    const int lane = tid & 63;
    const int wave = tid >> 6;
    const int j = (blockIdx.x - vb) * 4 + wave;
    const int lo = imax(j - 19, 0);
    const int hi = imin(j + 19, N - 1);
    const int ni = hi - lo + 1;
    float* aw = a_sh + wave * 40;
    if (lane < ni) {
      int i = lo + lane;
      aw[lane] = bandA[i * 40 + (j - imax(i - 19, 0))];
    }
    __syncthreads();
    f32x2 acc = {0.f, 0.f};
#pragma unroll 4
    for (int s = 0; s < ni; ++s) {
      float a = aw[s];
      u32 k = *(const u32*)(QKVa + (size_t)(lo + s) * 384 + 256 + lane * 2);
      acc.x += a * lo16(k);
      acc.y += a * hi16(k);
    }
    u32 o = (u32)f2bf(acc.x) | ((u32)f2bf(acc.y) << 16);
    *(u32*)(Ya + (size_t)j * 128 + lane * 2) = o;
  }
}

// ---------------------------------------------------------------------------
// Merged LayerNorm(O + X)*g + b -> bf16 ycomb. O is bf16, X fp32.
// Blocks [0,N): video (1024). Blocks [N,2N): audio (128).
// ---------------------------------------------------------------------------
__global__ __launch_bounds__(256) void vas_ln(
    const u16* __restrict__ Ov, const float* __restrict__ Xv,
    const float* __restrict__ gv, const float* __restrict__ bv_,
    const u16* __restrict__ Oa, const float* __restrict__ Xa,
    const float* __restrict__ ga, const float* __restrict__ ba,
    u16* __restrict__ out, int outStride, int N) {
  const int blk = blockIdx.x;
  const int tid = threadIdx.x, lane = tid & 63, wave = tid >> 6;
  __shared__ float shA[4], shB[4];

  if (blk < N) {
    const int row = blk;
    s16x4 o4 = ((const s16x4*)(Ov + (size_t)row * 1024))[tid];
    f32x4 x4 = ((const f32x4*)(Xv + (size_t)row * 1024))[tid];
    f32x4 v;
    v.x = bf2f((u16)o4.x) + x4.x;
    v.y = bf2f((u16)o4.y) + x4.y;
    v.z = bf2f((u16)o4.z) + x4.z;
    v.w = bf2f((u16)o4.w) + x4.w;
    float s = v.x + v.y + v.z + v.w;
    float s2 = v.x * v.x + v.y * v.y + v.z * v.z + v.w * v.w;
#pragma unroll
    for (int off = 32; off; off >>= 1) {
      s += __shfl_xor(s, off);
      s2 += __shfl_xor(s2, off);
    }
    if (lane == 0) { shA[wave] = s; shB[wave] = s2; }
    __syncthreads();
    float S = shA[0] + shA[1] + shA[2] + shA[3];
    float S2 = shB[0] + shB[1] + shB[2] + shB[3];
    float mu = S / 1024.f;
    float var = S2 / 1024.f - mu * mu;
    float inv = rsqrtf(var + 1e-6f);
    f32x4 gg = ((const f32x4*)gv)[tid];
    f32x4 bb = ((const f32x4*)bv_)[tid];
    s16x4 o;
    o.x = (short)f2bf((v.x - mu) * inv * gg.x + bb.x);
    o.y = (short)f2bf((v.y - mu) * inv * gg.y + bb.y);
    o.z = (short)f2bf((v.z - mu) * inv * gg.z + bb.z);
    o.w = (short)f2bf((v.w - mu) * inv * gg.w + bb.w);
    *(s16x4*)(out + (size_t)row * outStride + tid * 4) = o;
  } else {
    const int row = blk - N;
    float v = 0.f;
    if (tid < 128) v = bf2f(Oa[(size_t)row * 128 + tid]) + Xa[(size_t)row * 128 + tid];
    float s = v, s2 = v * v;
#pragma unroll
    for (int off = 32; off; off >>= 1) {
      s += __shfl_xor(s, off);
      s2 += __shfl_xor(s2, off);
    }
    if (lane == 0) { shA[wave] = s; shB[wave] = s2; }
    __syncthreads();
    float S = shA[0] + shA[1];
    float S2 = shB[0] + shB[1];
    float mu = S / 128.f;
    float var = S2 / 128.f - mu * mu;
    float inv = rsqrtf(var + 1e-6f);
    if (tid < 128)
      out[(size_t)row * outStride + 1024 + tid] =
          f2bf((v - mu) * inv * ga[tid] + ba[tid]);
  }
}

// ---------------------------------------------------------------------------
// head: score[row] = sigmoid( LN(H[row]) . kw + kb ), H bf16
// ---------------------------------------------------------------------------
__global__ __launch_bounds__(256) void vas_head(
    const u16* __restrict__ H, const float* __restrict__ g,
    const float* __restrict__ bb, const float* __restrict__ kw,
    const float* __restrict__ kb, float* __restrict__ score) {
  const int row = blockIdx.x;
  const int tid = threadIdx.x, lane = tid & 63, wave = tid >> 6;
  __shared__ float shA[4], shB[4];
  s16x4 raw = ((const s16x4*)(H + (size_t)row * 1024))[tid];
  f32x4 v;
  v.x = bf2f((u16)raw.x);
  v.y = bf2f((u16)raw.y);
  v.z = bf2f((u16)raw.z);
  v.w = bf2f((u16)raw.w);
  float s = v.x + v.y + v.z + v.w;
  float s2 = v.x * v.x + v.y * v.y + v.z * v.z + v.w * v.w;
#pragma unroll
  for (int off = 32; off; off >>= 1) {
    s += __shfl_xor(s, off);
    s2 += __shfl_xor(s2, off);
  }
  if (lane == 0) { shA[wave] = s; shB[wave] = s2; }
  __syncthreads();
  float S = shA[0] + shA[1] + shA[2] + shA[3];
  float S2 = shB[0] + shB[1] + shB[2] + shB[3];
  float mu = S / 1024.f;
  float var = S2 / 1024.f - mu * mu;
  float inv = rsqrtf(var + 1e-6f);
  f32x4 gg = ((const f32x4*)g)[tid];
  f32x4 bv = ((const f32x4*)bb)[tid];
  f32x4 kv = ((const f32x4*)kw)[tid];
  float p = ((v.x - mu) * inv * gg.x + bv.x) * kv.x +
            ((v.y - mu) * inv * gg.y + bv.y) * kv.y +
            ((v.z - mu) * inv * gg.z + bv.z) * kv.z +
            ((v.w - mu) * inv * gg.w + bv.w) * kv.w;
#pragma unroll
  for (int off = 32; off; off >>= 1) p += __shfl_xor(p, off);
  __syncthreads();
  if (lane == 0) shA[wave] = p;
  __syncthreads();
  if (tid == 0) {
    float P = shA[0] + shA[1] + shA[2] + shA[3] + kb[0];
    score[row] = 1.f / (1.f + __expf(-P));
  }
}

// ---------------------------------------------------------------------------
extern "C" void kernel_launch(void* const* d_in, const int* in_sizes, int n_in,
                              void* d_out, int out_size, void* d_ws, size_t ws_size,
                              hipStream_t stream) {
  const float* x = (const float*)d_in[0];
  const float* xa = (const float*)d_in[1];
  const float* Wk_v = (const float*)d_in[4];
  const float* Wq_v = (const float*)d_in[5];
  const float* Wv_v = (const float*)d_in[6];
  const float* Wo_v = (const float*)d_in[7];
  const float* Wk_a = (const float*)d_in[8];
  const float* Wq_a = (const float*)d_in[9];
  const float* Wv_a = (const float*)d_in[10];
  const float* Wo_a = (const float*)d_in[11];
  const float* ka_w = (const float*)d_in[12];
  const float* ka_b = (const float*)d_in[13];
  const float* kd_w = (const float*)d_in[14];
  const float* kd_b = (const float*)d_in[15];
  const float* ln_y_g = (const float*)d_in[16];
  const float* ln_y_b = (const float*)d_in[17];
  const float* ln_ya_g = (const float*)d_in[18];
  const float* ln_ya_b = (const float*)d_in[19];
  const float* ln_ka_g = (const float*)d_in[20];
  const float* ln_ka_b = (const float*)d_in[21];

  const int N = in_sizes[0] / 1024;  // 6144
  const int MV = 1024, MA = 128, MH = 1152;

  char* wsb = (char*)d_ws;
  size_t off = 0;
  auto alloc = [&](size_t bytes) -> void* {
    void* p = wsb + off;
    off += (bytes + 255) & ~(size_t)255;
    return p;
  };
  u16* xf_b    = (u16*)alloc((size_t)N * MV * 2);
  u16* xa_b    = (u16*)alloc((size_t)N * MA * 2);
  u16* wqkv_b  = (u16*)alloc((size_t)3 * MV * MV * 2);
  u16* wqkva_b = (u16*)alloc((size_t)3 * MA * MA * 2);
  u16* wov_b   = (u16*)alloc((size_t)MV * MV * 2);
  u16* woa_b   = (u16*)alloc((size_t)MA * MA * 2);
  u16* kaw_b   = (u16*)alloc((size_t)1024 * MH * 2);
  u16* QKVv    = (u16*)alloc((size_t)N * 3 * MV * 2);  // bf16, cols K|Q|V
  u16* QKVa    = (u16*)alloc((size_t)N * 3 * MA * 2);
  float* bandV = (float*)alloc((size_t)N * 40 * 4);
  float* bandA = (float*)alloc((size_t)N * 40 * 4);
  u16* yv_b = (u16*)alloc((size_t)N * MV * 2);
  u16* ya_b = (u16*)alloc((size_t)N * MA * 2);
  u16* ov_b = (u16*)alloc((size_t)N * MV * 2);
  u16* oa_b = (u16*)alloc((size_t)N * MA * 2);
  u16* ycomb_b = (u16*)alloc((size_t)N * MH * 2);
  u16* h_b = (u16*)alloc((size_t)N * 1024 * 2);

  float* dout = (float*)d_out;
  float* attBase = dout + N;

  // 1) fused cast pass
  {
    CastTab t;
    int c = 0, cum = 0;
    auto seg = [&](const float* s, u16* d, size_t n) {
      t.src[c] = s; t.dst[c] = d; t.start[c] = cum; cum += (int)(n / 4); ++c;
    };
    seg(x, xf_b, (size_t)N * MV);
    seg(xa, xa_b, (size_t)N * MA);
    seg(Wk_v, wqkv_b + 0 * MV * MV, (size_t)MV * MV);
    seg(Wq_v, wqkv_b + 1 * MV * MV, (size_t)MV * MV);
    seg(Wv_v, wqkv_b + 2 * MV * MV, (size_t)MV * MV);
    seg(Wk_a, wqkva_b + 0 * MA * MA, (size_t)MA * MA);
    seg(Wq_a, wqkva_b + 1 * MA * MA, (size_t)MA * MA);
    seg(Wv_a, wqkva_b + 2 * MA * MA, (size_t)MA * MA);
    seg(Wo_v, wov_b, (size_t)MV * MV);
    seg(Wo_a, woa_b, (size_t)MA * MA);
    seg(ka_w, kaw_b, (size_t)1024 * MH);
    t.start[c] = cum;
    vas_cast<<<(cum + 255) / 256, 256, 0, stream>>>(t, cum);
  }

  // 2) fused QKV projections (video + audio in one grid), bf16 out
  {
    GemmP pv = {xf_b, wqkv_b, QKVv, nullptr, N, 3 * MV, MV, 2};
    GemmP pa = {xa_b, wqkva_b, QKVa, nullptr, N, 3 * MA, MA, 2};
    int bv = (N / 128) * (3 * MV / 128);
    int ba = (N / 128) * (3 * MA / 128);
    vas_gemm2<<<bv + ba, 256, 0, stream>>>(pv, pa, bv);
  }

  // 3) fused banded softmax: bands + full att_comb rows (video [0,N), audio [N,2N))
  vas_battn<<<N / 2, 256, 0, stream>>>(QKVv, QKVa, bandV, bandA, attBase, N, 0.06f, N / 4);

  // 4) fused apply: y = att.T @ V
  vas_apply<<<N / JT + N / 4, 256, 0, stream>>>(QKVv, QKVa, bandV, bandA, yv_b, ya_b, N, N / JT);

  // 5) fused output projections, bf16 out
  {
    GemmP pv = {yv_b, wov_b, ov_b, nullptr, N, MV, MV, 2};
    GemmP pa = {ya_b, woa_b, oa_b, nullptr, N, MA, MA, 2};
    int bv = (N / 128) * (MV / 128);
    int ba = (N / 128) * (MA / 128);
    vas_gemm2<<<bv + ba, 256, 0, stream>>>(pv, pa, bv);
  }

  // 6) merged LN(o + x) -> ycomb bf16
  vas_ln<<<2 * N, 256, 0, stream>>>(ov_b, x, ln_y_g, ln_y_b,
                                    oa_b, xa, ln_ya_g, ln_ya_b,
                                    ycomb_b, MH, N);

  // 7) h = relu(ycomb @ ka_w.T + ka_b), bf16 out
  {
    GemmP ph = {ycomb_b, kaw_b, h_b, ka_b, N, 1024, MH, 1};
    int bh = (N / 128) * (1024 / 128);
    vas_gemm2<<<bh, 256, 0, stream>>>(ph, ph, bh);
  }

  // 8) score
  vas_head<<<N, 256, 0, stream>>>(h_b, ln_ka_g, ln_ka_b, kd_w, kd_b, dout);
}

// Round 7
// 598.898 us; speedup vs baseline: 1.3075x; 1.0163x over previous
//
#include <hip/hip_runtime.h>
#include <stdint.h>

typedef unsigned short u16;
typedef unsigned int u32;
typedef __attribute__((ext_vector_type(8))) short bf16x8;
typedef __attribute__((ext_vector_type(4))) short s16x4;
typedef __attribute__((ext_vector_type(4))) float f32x4;
typedef __attribute__((ext_vector_type(2))) float f32x2;

#define DEV __device__ __forceinline__

DEV u16 f2bf(float f) {
  union { float f; unsigned u; } v; v.f = f;
  unsigned r = v.u + 0x7fffu + ((v.u >> 16) & 1u);
  return (u16)(r >> 16);
}
DEV float bf2f(u16 h) {
  union { u32 u; float f; } v; v.u = ((u32)h) << 16; return v.f;
}
DEV float lo16(u32 w) { union { u32 u; float f; } v; v.u = w << 16; return v.f; }
DEV float hi16(u32 w) { union { u32 u; float f; } v; v.u = w & 0xFFFF0000u; return v.f; }
DEV int imax(int a, int b) { return a > b ? a : b; }
DEV int imin(int a, int b) { return a < b ? a : b; }

DEV void g2lds16(const u16* g, u16* l) {
  __builtin_amdgcn_global_load_lds(
      (const __attribute__((address_space(1))) void*)g,
      (__attribute__((address_space(3))) void*)l, 16, 0, 0);
}

// ---------------------------------------------------------------------------
// one-shot multi-segment f32 -> bf16 cast
// ---------------------------------------------------------------------------
#define NSEG 11
struct CastTab {
  const float* src[NSEG];
  u16* dst[NSEG];
  int start[NSEG + 1];
};

__global__ __launch_bounds__(256) void vas_cast(CastTab t, int total4) {
  int idx = blockIdx.x * 256 + threadIdx.x;
  if (idx >= total4) return;
  int s = 0;
#pragma unroll
  for (int k = 1; k < NSEG; ++k)
    if (idx >= t.start[k]) s = k;
  int local = idx - t.start[s];
  f32x4 f = ((const f32x4*)t.src[s])[local];
  s16x4 o;
  o.x = (short)f2bf(f.x);
  o.y = (short)f2bf(f.y);
  o.z = (short)f2bf(f.z);
  o.w = (short)f2bf(f.w);
  ((s16x4*)t.dst[s])[local] = o;
}

// ---------------------------------------------------------------------------
// Dual bf16 GEMM, BK=64 (two m97-layout K-half LDS buffers per operand;
// 2 barriers per 64 K instead of 4). Group-m swizzle for L2.
// mode 0: f32 out; 1: bf16 relu+bias; 2: bf16 plain. K % 64 == 0.
// ---------------------------------------------------------------------------
struct GemmP {
  const u16* A;
  const u16* W;
  void* C;
  const float* bias;
  int M, Nn, K, mode;
};

__global__ __launch_bounds__(256) void vas_gemm2(GemmP p0, GemmP p1, int split) {
  const bool first = blockIdx.x < (u32)split;
  GemmP p = first ? p0 : p1;
  const int bid = first ? blockIdx.x : blockIdx.x - split;

  __shared__ u16 As[2][128 * 32];
  __shared__ u16 Ws[2][128 * 32];
  const int tid = threadIdx.x;
  const int lane = tid & 63;
  const int wave = tid >> 6;

  const int Mb = p.M >> 7, Nb = p.Nn >> 7;
  const int GM = 8;
  int per = GM * Nb;
  int g = bid / per;
  int rem = bid - g * per;
  int gm = imin(GM, Mb - g * GM);
  int mblk = g * GM + rem % gm;
  int nblk = rem / gm;
  const int m0 = mblk * 128;
  const int n0 = nblk * 128;
  const int wm = (wave >> 1) * 64;
  const int wn = (wave & 1) * 64;

  // wave-uniform staging decode: waves 0,1 stage A (khalf 0,1), waves 2,3 W.
  const int smat = wave >> 1;          // 0: A, 1: W
  const int skh = wave & 1;            // K-half
  const u16* ssrc = smat ? p.W : p.A;
  const int sbase = smat ? n0 : m0;
  u16* sdstBase = (smat ? &Ws[skh][0] : &As[skh][0]) + lane * 8;
  const int srow = lane >> 2;          // 0..15 within 16-row panel
  const int scol = (lane & 3) * 8;

  f32x4 acc[4][4] = {};

  for (int k0 = 0; k0 < p.K; k0 += 64) {
#pragma unroll
    for (int u = 0; u < 8; ++u) {
      int r0 = u * 16;
      g2lds16(ssrc + (size_t)(sbase + r0 + srow) * p.K + (k0 + skh * 32 + scol),
              sdstBase + r0 * 32);
    }
    __syncthreads();
#pragma unroll
    for (int kk = 0; kk < 2; ++kk) {
      bf16x8 af[4], bfr[4];
#pragma unroll
      for (int t = 0; t < 4; ++t)
        af[t] = *(const bf16x8*)(&As[kk][0] + (wm + t * 16 + (lane & 15)) * 32 + (lane >> 4) * 8);
#pragma unroll
      for (int t = 0; t < 4; ++t)
        bfr[t] = *(const bf16x8*)(&Ws[kk][0] + (wn + t * 16 + (lane & 15)) * 32 + (lane >> 4) * 8);
#pragma unroll
      for (int mi = 0; mi < 4; ++mi)
#pragma unroll
        for (int ni = 0; ni < 4; ++ni)
          acc[mi][ni] = __builtin_amdgcn_mfma_f32_16x16x32_bf16(af[mi], bfr[ni], acc[mi][ni], 0, 0, 0);
    }
    __syncthreads();
  }

#pragma unroll
  for (int mi = 0; mi < 4; ++mi) {
#pragma unroll
    for (int ni = 0; ni < 4; ++ni) {
      int col = n0 + wn + ni * 16 + (lane & 15);
      float bv = p.bias ? p.bias[col] : 0.f;
#pragma unroll
      for (int r = 0; r < 4; ++r) {
        int row = m0 + wm + mi * 16 + (lane >> 4) * 4 + r;
        float vv = acc[mi][ni][r] + bv;
        size_t idx = (size_t)row * p.Nn + col;
        if (p.mode == 0) ((float*)p.C)[idx] = vv;
        else if (p.mode == 1) ((u16*)p.C)[idx] = f2bf(fmaxf(vv, 0.f));
        else ((u16*)p.C)[idx] = f2bf(vv);
      }
    }
  }
}

// ---------------------------------------------------------------------------
// Fused banded attention softmax (bf16 Q/K). Blocks [0,vb): video rows -> band
// + att cols [0,N). Blocks [vb,2vb): audio rows -> band + att cols [N,2N).
// One wave per row, 4 rows/block. QKV layout cols K|Q|V.
// ---------------------------------------------------------------------------
__global__ __launch_bounds__(256) void vas_battn(
    const u16* __restrict__ QKVv, const u16* __restrict__ QKVa,
    float* __restrict__ bandV, float* __restrict__ bandA,
    float* __restrict__ attBase, int N, float scale, int vb) {
  const int lane = threadIdx.x & 63;
  const int wave = threadIdx.x >> 6;
  const bool video = blockIdx.x < (u32)vb;
  const int i = (video ? blockIdx.x : blockIdx.x - vb) * 4 + wave;
  const int lo = imax(i - 19, 0);
  const int hi = imin(i + 19, N - 1);
  const int nj = hi - lo + 1;
  float logit = 0.f;
  __shared__ float a_sh[4][40];

  if (video) {
    float qf[16];
    const u16* qrow = QKVv + (size_t)i * 3072 + 1024;
#pragma unroll
    for (int c = 0; c < 2; ++c) {
      bf16x8 qv = *(const bf16x8*)(qrow + c * 512 + lane * 8);
      const u32* qw = (const u32*)&qv;
#pragma unroll
      for (int t = 0; t < 4; ++t) {
        qf[c * 8 + 2 * t] = lo16(qw[t]);
        qf[c * 8 + 2 * t + 1] = hi16(qw[t]);
      }
    }
#pragma unroll 2
    for (int s = 0; s < nj; ++s) {
      const u16* kr = QKVv + (size_t)(lo + s) * 3072;
      float p = 0.f;
#pragma unroll
      for (int c = 0; c < 2; ++c) {
        bf16x8 kv = *(const bf16x8*)(kr + c * 512 + lane * 8);
        const u32* kw = (const u32*)&kv;
#pragma unroll
        for (int t = 0; t < 4; ++t)
          p += lo16(kw[t]) * qf[c * 8 + 2 * t] + hi16(kw[t]) * qf[c * 8 + 2 * t + 1];
      }
#pragma unroll
      for (int off = 32; off; off >>= 1) p += __shfl_xor(p, off);
      if (lane == s) logit = p;
    }
  } else {
    u32 q = *(const u32*)(QKVa + (size_t)i * 384 + 128 + lane * 2);
    float q0 = lo16(q), q1 = hi16(q);
#pragma unroll 2
    for (int s = 0; s < nj; ++s) {
      u32 k = *(const u32*)(QKVa + (size_t)(lo + s) * 384 + lane * 2);
      float p = lo16(k) * q0 + hi16(k) * q1;
#pragma unroll
      for (int off = 32; off; off >>= 1) p += __shfl_xor(p, off);
      if (lane == s) logit = p;
    }
  }

  logit *= scale;
  float v = (lane < nj) ? logit : -3.4e38f;
  float mx = v;
#pragma unroll
  for (int off = 32; off; off >>= 1) mx = fmaxf(mx, __shfl_xor(mx, off));
  float e = (lane < nj) ? __expf(v - mx) : 0.f;
  float den = e;
#pragma unroll
  for (int off = 32; off; off >>= 1) den += __shfl_xor(den, off);
  float att = (lane < nj) ? e / den : 0.f;
  float* band = video ? bandV : bandA;
  if (lane < 40) {
    band[i * 40 + lane] = att;
    a_sh[wave][lane] = att;  // wave-synchronous: same wave reads below
  }

  f32x4* rowp = (f32x4*)(attBase + (size_t)i * 2 * N + (video ? 0 : N));
  const int nchunks = N / 4;
  const int cLo = lo >> 2, cHi = hi >> 2;
  for (int c = lane; c < nchunks; c += 64) {
    f32x4 o = {0.f, 0.f, 0.f, 0.f};
    if (c >= cLo && c <= cHi) {
      int col0 = c * 4;
#pragma unroll
      for (int e2 = 0; e2 < 4; ++e2) {
        int col = col0 + e2;
        if (col >= lo && col <= hi) o[e2] = a_sh[wave][col - lo];
      }
    }
    rowp[c] = o;
  }
}

// ---------------------------------------------------------------------------
// Fused apply: y[j,:] = sum_i att[i,j] * V[i,:] (att.T @ V), bf16 V, bf16 out.
// Blocks [0,vb): video, JT j's per block. Blocks [vb, vb+N/4): audio, wave/j.
// ---------------------------------------------------------------------------
#define JT 8
__global__ __launch_bounds__(256) void vas_apply(
    const u16* __restrict__ QKVv, const u16* __restrict__ QKVa,
    const float* __restrict__ bandV, const float* __restrict__ bandA,
    u16* __restrict__ Yv, u16* __restrict__ Ya, int N, int vb) {
  const int tid = threadIdx.x;
  __shared__ float a_sh[(JT + 38) * JT];

  if (blockIdx.x < (u32)vb) {
    const int j0 = blockIdx.x * JT;
    const int base = j0 - 19;
    for (int idx = tid; idx < (JT + 38) * JT; idx += 256) {
      int s = idx / JT, jj = idx % JT;
      int i = base + s;
      int j = j0 + jj;
      float w = 0.f;
      if (i >= 0 && i < N) {
        int d = j - i;
        if (d > -20 && d < 20) w = bandV[i * 40 + (j - imax(i - 19, 0))];
      }
      a_sh[s * JT + jj] = w;
    }
    __syncthreads();

    f32x4 acc[JT] = {};
    const int sLo = imax(0, -base);
    const int sHi = imin(JT + 38, N - base);
    for (int s = sLo; s < sHi; ++s) {
      s16x4 raw = *(const s16x4*)(QKVv + (size_t)(base + s) * 3072 + 2048 + tid * 4);
      f32x4 vv;
      vv.x = bf2f((u16)raw.x);
      vv.y = bf2f((u16)raw.y);
      vv.z = bf2f((u16)raw.z);
      vv.w = bf2f((u16)raw.w);
#pragma unroll
      for (int jj = 0; jj < JT; ++jj) {
        float a = a_sh[s * JT + jj];
        acc[jj].x += a * vv.x;
        acc[jj].y += a * vv.y;
        acc[jj].z += a * vv.z;
        acc[jj].w += a * vv.w;
      }
    }
#pragma unroll
    for (int jj = 0; jj < JT; ++jj) {
      s16x4 o;
      o.x = (short)f2bf(acc[jj].x);
      o.y = (short)f2bf(acc[jj].y);
      o.z = (short)f2bf(acc[jj].z);
      o.w = (short)f2bf(acc[jj].w);
      *(s16x4*)(Yv + (size_t)(j0 + jj) * 1024 + tid * 4) = o;
    }
  } else {
    const int lane = tid & 63;
    const int wave = tid >> 6;
    const int j = (blockIdx.x - vb) * 4 + wave;
    const int lo = imax(j - 19, 0);
    const int hi = imin(j + 19, N - 1);
    const int ni = hi - lo + 1;
    float* aw = a_sh + wave * 40;
    if (lane < ni) {
      int i = lo + lane;
      aw[lane] = bandA[i * 40 + (j - imax(i - 19, 0))];
    }
    __syncthreads();
    f32x2 acc = {0.f, 0.f};
#pragma unroll 4
    for (int s = 0; s < ni; ++s) {
      float a = aw[s];
      u32 k = *(const u32*)(QKVa + (size_t)(lo + s) * 384 + 256 + lane * 2);
      acc.x += a * lo16(k);
      acc.y += a * hi16(k);
    }
    u32 o = (u32)f2bf(acc.x) | ((u32)f2bf(acc.y) << 16);
    *(u32*)(Ya + (size_t)j * 128 + lane * 2) = o;
  }
}

// ---------------------------------------------------------------------------
// Merged LayerNorm(O + X)*g + b -> bf16 ycomb. O bf16, X fp32.
// ---------------------------------------------------------------------------
__global__ __launch_bounds__(256) void vas_ln(
    const u16* __restrict__ Ov, const float* __restrict__ Xv,
    const float* __restrict__ gv, const float* __restrict__ bv_,
    const u16* __restrict__ Oa, const float* __restrict__ Xa,
    const float* __restrict__ ga, const float* __restrict__ ba,
    u16* __restrict__ out, int outStride, int N) {
  const int blk = blockIdx.x;
  const int tid = threadIdx.x, lane = tid & 63, wave = tid >> 6;
  __shared__ float shA[4], shB[4];

  if (blk < N) {
    const int row = blk;
    s16x4 o4 = ((const s16x4*)(Ov + (size_t)row * 1024))[tid];
    f32x4 x4 = ((const f32x4*)(Xv + (size_t)row * 1024))[tid];
    f32x4 v;
    v.x = bf2f((u16)o4.x) + x4.x;
    v.y = bf2f((u16)o4.y) + x4.y;
    v.z = bf2f((u16)o4.z) + x4.z;
    v.w = bf2f((u16)o4.w) + x4.w;
    float s = v.x + v.y + v.z + v.w;
    float s2 = v.x * v.x + v.y * v.y + v.z * v.z + v.w * v.w;
#pragma unroll
    for (int off = 32; off; off >>= 1) {
      s += __shfl_xor(s, off);
      s2 += __shfl_xor(s2, off);
    }
    if (lane == 0) { shA[wave] = s; shB[wave] = s2; }
    __syncthreads();
    float S = shA[0] + shA[1] + shA[2] + shA[3];
    float S2 = shB[0] + shB[1] + shB[2] + shB[3];
    float mu = S / 1024.f;
    float var = S2 / 1024.f - mu * mu;
    float inv = rsqrtf(var + 1e-6f);
    f32x4 gg = ((const f32x4*)gv)[tid];
    f32x4 bb = ((const f32x4*)bv_)[tid];
    s16x4 o;
    o.x = (short)f2bf((v.x - mu) * inv * gg.x + bb.x);
    o.y = (short)f2bf((v.y - mu) * inv * gg.y + bb.y);
    o.z = (short)f2bf((v.z - mu) * inv * gg.z + bb.z);
    o.w = (short)f2bf((v.w - mu) * inv * gg.w + bb.w);
    *(s16x4*)(out + (size_t)row * outStride + tid * 4) = o;
  } else {
    const int row = blk - N;
    float v = 0.f;
    if (tid < 128) v = bf2f(Oa[(size_t)row * 128 + tid]) + Xa[(size_t)row * 128 + tid];
    float s = v, s2 = v * v;
#pragma unroll
    for (int off = 32; off; off >>= 1) {
      s += __shfl_xor(s, off);
      s2 += __shfl_xor(s2, off);
    }
    if (lane == 0) { shA[wave] = s; shB[wave] = s2; }
    __syncthreads();
    float S = shA[0] + shA[1];
    float S2 = shB[0] + shB[1];
    float mu = S / 128.f;
    float var = S2 / 128.f - mu * mu;
    float inv = rsqrtf(var + 1e-6f);
    if (tid < 128)
      out[(size_t)row * outStride + 1024 + tid] =
          f2bf((v - mu) * inv * ga[tid] + ba[tid]);
  }
}

// ---------------------------------------------------------------------------
// head: score[row] = sigmoid( LN(H[row]) . kw + kb ), H bf16
// ---------------------------------------------------------------------------
__global__ __launch_bounds__(256) void vas_head(
    const u16* __restrict__ H, const float* __restrict__ g,
    const float* __restrict__ bb, const float* __restrict__ kw,
    const float* __restrict__ kb, float* __restrict__ score) {
  const int row = blockIdx.x;
  const int tid = threadIdx.x, lane = tid & 63, wave = tid >> 6;
  __shared__ float shA[4], shB[4];
  s16x4 raw = ((const s16x4*)(H + (size_t)row * 1024))[tid];
  f32x4 v;
  v.x = bf2f((u16)raw.x);
  v.y = bf2f((u16)raw.y);
  v.z = bf2f((u16)raw.z);
  v.w = bf2f((u16)raw.w);
  float s = v.x + v.y + v.z + v.w;
  float s2 = v.x * v.x + v.y * v.y + v.z * v.z + v.w * v.w;
#pragma unroll
  for (int off = 32; off; off >>= 1) {
    s += __shfl_xor(s, off);
    s2 += __shfl_xor(s2, off);
  }
  if (lane == 0) { shA[wave] = s; shB[wave] = s2; }
  __syncthreads();
  float S = shA[0] + shA[1] + shA[2] + shA[3];
  float S2 = shB[0] + shB[1] + shB[2] + shB[3];
  float mu = S / 1024.f;
  float var = S2 / 1024.f - mu * mu;
  float inv = rsqrtf(var + 1e-6f);
  f32x4 gg = ((const f32x4*)g)[tid];
  f32x4 bv = ((const f32x4*)bb)[tid];
  f32x4 kv = ((const f32x4*)kw)[tid];
  float p = ((v.x - mu) * inv * gg.x + bv.x) * kv.x +
            ((v.y - mu) * inv * gg.y + bv.y) * kv.y +
            ((v.z - mu) * inv * gg.z + bv.z) * kv.z +
            ((v.w - mu) * inv * gg.w + bv.w) * kv.w;
#pragma unroll
  for (int off = 32; off; off >>= 1) p += __shfl_xor(p, off);
  __syncthreads();
  if (lane == 0) shA[wave] = p;
  __syncthreads();
  if (tid == 0) {
    float P = shA[0] + shA[1] + shA[2] + shA[3] + kb[0];
    score[row] = 1.f / (1.f + __expf(-P));
  }
}

// ---------------------------------------------------------------------------
extern "C" void kernel_launch(void* const* d_in, const int* in_sizes, int n_in,
                              void* d_out, int out_size, void* d_ws, size_t ws_size,
                              hipStream_t stream) {
  const float* x = (const float*)d_in[0];
  const float* xa = (const float*)d_in[1];
  const float* Wk_v = (const float*)d_in[4];
  const float* Wq_v = (const float*)d_in[5];
  const float* Wv_v = (const float*)d_in[6];
  const float* Wo_v = (const float*)d_in[7];
  const float* Wk_a = (const float*)d_in[8];
  const float* Wq_a = (const float*)d_in[9];
  const float* Wv_a = (const float*)d_in[10];
  const float* Wo_a = (const float*)d_in[11];
  const float* ka_w = (const float*)d_in[12];
  const float* ka_b = (const float*)d_in[13];
  const float* kd_w = (const float*)d_in[14];
  const float* kd_b = (const float*)d_in[15];
  const float* ln_y_g = (const float*)d_in[16];
  const float* ln_y_b = (const float*)d_in[17];
  const float* ln_ya_g = (const float*)d_in[18];
  const float* ln_ya_b = (const float*)d_in[19];
  const float* ln_ka_g = (const float*)d_in[20];
  const float* ln_ka_b = (const float*)d_in[21];

  const int N = in_sizes[0] / 1024;  // 6144
  const int MV = 1024, MA = 128, MH = 1152;

  char* wsb = (char*)d_ws;
  size_t off = 0;
  auto alloc = [&](size_t bytes) -> void* {
    void* p = wsb + off;
    off += (bytes + 255) & ~(size_t)255;
    return p;
  };
  u16* xf_b    = (u16*)alloc((size_t)N * MV * 2);
  u16* xa_b    = (u16*)alloc((size_t)N * MA * 2);
  u16* wqkv_b  = (u16*)alloc((size_t)3 * MV * MV * 2);
  u16* wqkva_b = (u16*)alloc((size_t)3 * MA * MA * 2);
  u16* wov_b   = (u16*)alloc((size_t)MV * MV * 2);
  u16* woa_b   = (u16*)alloc((size_t)MA * MA * 2);
  u16* kaw_b   = (u16*)alloc((size_t)1024 * MH * 2);
  u16* QKVv    = (u16*)alloc((size_t)N * 3 * MV * 2);  // bf16, cols K|Q|V
  u16* QKVa    = (u16*)alloc((size_t)N * 3 * MA * 2);
  float* bandV = (float*)alloc((size_t)N * 40 * 4);
  float* bandA = (float*)alloc((size_t)N * 40 * 4);
  u16* yv_b = (u16*)alloc((size_t)N * MV * 2);
  u16* ya_b = (u16*)alloc((size_t)N * MA * 2);
  u16* ov_b = (u16*)alloc((size_t)N * MV * 2);
  u16* oa_b = (u16*)alloc((size_t)N * MA * 2);
  u16* ycomb_b = (u16*)alloc((size_t)N * MH * 2);
  u16* h_b = (u16*)alloc((size_t)N * 1024 * 2);

  float* dout = (float*)d_out;
  float* attBase = dout + N;

  // 1) fused cast pass
  {
    CastTab t;
    int c = 0, cum = 0;
    auto seg = [&](const float* s, u16* d, size_t n) {
      t.src[c] = s; t.dst[c] = d; t.start[c] = cum; cum += (int)(n / 4); ++c;
    };
    seg(x, xf_b, (size_t)N * MV);
    seg(xa, xa_b, (size_t)N * MA);
    seg(Wk_v, wqkv_b + 0 * MV * MV, (size_t)MV * MV);
    seg(Wq_v, wqkv_b + 1 * MV * MV, (size_t)MV * MV);
    seg(Wv_v, wqkv_b + 2 * MV * MV, (size_t)MV * MV);
    seg(Wk_a, wqkva_b + 0 * MA * MA, (size_t)MA * MA);
    seg(Wq_a, wqkva_b + 1 * MA * MA, (size_t)MA * MA);
    seg(Wv_a, wqkva_b + 2 * MA * MA, (size_t)MA * MA);
    seg(Wo_v, wov_b, (size_t)MV * MV);
    seg(Wo_a, woa_b, (size_t)MA * MA);
    seg(ka_w, kaw_b, (size_t)1024 * MH);
    t.start[c] = cum;
    vas_cast<<<(cum + 255) / 256, 256, 0, stream>>>(t, cum);
  }

  // 2) fused QKV projections (video + audio in one grid), bf16 out
  {
    GemmP pv = {xf_b, wqkv_b, QKVv, nullptr, N, 3 * MV, MV, 2};
    GemmP pa = {xa_b, wqkva_b, QKVa, nullptr, N, 3 * MA, MA, 2};
    int bv = (N / 128) * (3 * MV / 128);
    int ba = (N / 128) * (3 * MA / 128);
    vas_gemm2<<<bv + ba, 256, 0, stream>>>(pv, pa, bv);
  }

  // 3) fused banded softmax: bands + full att_comb rows
  vas_battn<<<N / 2, 256, 0, stream>>>(QKVv, QKVa, bandV, bandA, attBase, N, 0.06f, N / 4);

  // 4) fused apply: y = att.T @ V
  vas_apply<<<N / JT + N / 4, 256, 0, stream>>>(QKVv, QKVa, bandV, bandA, yv_b, ya_b, N, N / JT);

  // 5) fused output projections, bf16 out
  {
    GemmP pv = {yv_b, wov_b, ov_b, nullptr, N, MV, MV, 2};
    GemmP pa = {ya_b, woa_b, oa_b, nullptr, N, MA, MA, 2};
    int bv = (N / 128) * (MV / 128);
    int ba = (N / 128) * (MA / 128);
    vas_gemm2<<<bv + ba, 256, 0, stream>>>(pv, pa, bv);
  }

  // 6) merged LN(o + x) -> ycomb bf16
  vas_ln<<<2 * N, 256, 0, stream>>>(ov_b, x, ln_y_g, ln_y_b,
                                    oa_b, xa, ln_ya_g, ln_ya_b,
                                    ycomb_b, MH, N);

  // 7) h = relu(ycomb @ ka_w.T + ka_b), bf16 out
  {
    GemmP ph = {ycomb_b, kaw_b, h_b, ka_b, N, 1024, MH, 1};
    int bh = (N / 128) * (1024 / 128);
    vas_gemm2<<<bh, 256, 0, stream>>>(ph, ph, bh);
  }

  // 8) score
  vas_head<<<N, 256, 0, stream>>>(h_b, ln_ka_g, ln_ka_b, kd_w, kd_b, dout);
}